// Round 5
// baseline (1288.971 us; speedup 1.0000x reference)
//
#include <hip/hip_runtime.h>

typedef _Float16 half_t;
typedef _Float16 half8 __attribute__((ext_vector_type(8)));
typedef float f32x16 __attribute__((ext_vector_type(16)));

#define DEVINL __device__ __forceinline__

// ---------- constants ----------
#define INV_S3 0.57735026918962576f   // 1/sqrt(3)
#define INV_S2 0.70710678118654752f   // 1/sqrt(2)
#define C_OLD  0.89442719099991588f   // 1/sqrt(1.25)
#define A_COLD 0.44721359549995794f   // 0.5/sqrt(1.25)
#define SC_ENV 0.05590169943749474f   // (1/sqrt(20)) * (1/4)
#define SC_FS  0.17677669529663688f   // 1/sqrt(32)
#define SC_FV  0.14433756729740643f   // 1/sqrt(48)
#define SC_OUT 0.03608439182435161f   // (1/4)/sqrt(48)
#define DS 136                         // Dstage row stride (halfs); 136*2B rows 16B-aligned
#define VPH 146                        // per-edge V stride in LDS (halfs)

DEVINL float silu_f(float x) { return x / (1.f + __expf(-x)); }

DEVINL float poly_cut(float u) {
    float u2 = u * u, u4 = u2 * u2, u6 = u4 * u2;
    float f = 1.f - 28.f * u6 + 48.f * u6 * u - 21.f * u6 * u2;
    return (u < 1.f) ? f : 0.f;
}

// =====================================================================
// MFMA building blocks. M=32 edges per block.
// Afrag (LDS fp16): cell(kblk,m) at halfs[(kblk*32+m)*8 + j], k = kblk*8+j
// Bfrag (global fp16): cell(ntile,kblk,n) at halfs[((ntile*KB+kblk)*32+n)*8 + j]
// D: col = lane&31 (within ntile), row m = (r&3)+8*(r>>2)+4*(lane>>5).
// Dual accumulators: halve the dependent MFMA chain (latency-bound regime).
// =====================================================================
template <int KB>  // KB = K/8
DEVINL f32x16 mfma_stage(const half_t* __restrict__ Afrag,
                         const half_t* __restrict__ Bfrag, int ntile, int lane) {
    const int nq = lane & 31, q = lane >> 5;
    const half_t* ap = Afrag + q * 256 + nq * 8;
    const half_t* bp = Bfrag + ((size_t)ntile * KB + q) * 256 + nq * 8;
    constexpr int H = KB / 2;
    f32x16 acc0, acc1;
#pragma unroll
    for (int i = 0; i < 16; ++i) { acc0[i] = 0.f; acc1[i] = 0.f; }
#pragma unroll
    for (int h = 0; h < H; h += 2) {
        half8 a0 = *reinterpret_cast<const half8*>(ap + h * 512);
        half8 b0 = *reinterpret_cast<const half8*>(bp + h * 512);
        acc0 = __builtin_amdgcn_mfma_f32_32x32x16_f16(a0, b0, acc0, 0, 0, 0);
        if (h + 1 < H) {
            half8 a1 = *reinterpret_cast<const half8*>(ap + (h + 1) * 512);
            half8 b1 = *reinterpret_cast<const half8*>(bp + (h + 1) * 512);
            acc1 = __builtin_amdgcn_mfma_f32_32x32x16_f16(a1, b1, acc1, 0, 0, 0);
        }
    }
    if constexpr (H > 1) acc0 = acc0 + acc1;
    return acc0;
}

DEVINL void dwrite(half_t* __restrict__ DstH, const f32x16& acc, int lane, int col0) {
    const int n = col0 + (lane & 31), q = lane >> 5;
#pragma unroll
    for (int r = 0; r < 16; ++r) {
        int m = (r & 3) + 8 * (r >> 2) + 4 * q;
        DstH[m * DS + n] = (half_t)acc[r];
    }
}

// DstH (128 cols, fp16 pre-act) -> silu -> fp16 Afrag. 256 threads, 512 cells.
DEVINL void repack_silu(const half_t* __restrict__ DstH, half_t* __restrict__ Afrag,
                        int t) {
#pragma unroll
    for (int c = 0; c < 2; ++c) {
        int cell = t + c * 256;
        int kblk = cell >> 5, m = cell & 31;
        half8 x = *reinterpret_cast<const half8*>(DstH + m * DS + kblk * 8);
        half8 v;
#pragma unroll
        for (int j = 0; j < 8; ++j) v[j] = (half_t)silu_f((float)x[j]);
        *reinterpret_cast<half8*>(Afrag + cell * 8) = v;
    }
}

// =====================================================================
__global__ __launch_bounds__(256) void k_zero(float* __restrict__ p, int n) {
    int i = blockIdx.x * 256 + threadIdx.x;
    if (i < n) p[i] = 0.f;
}

// =====================================================================
// Weight pack: f32 [K][N] row-major -> fp16 B-fragment layout (N padded to 32).
// =====================================================================
struct PackArgs {
    const float* src[14];
    half_t* dst[14];
    int K[14];
    int N[14];
};

__global__ __launch_bounds__(256) void k_pack(PackArgs pa) {
    int mi = blockIdx.y;
    int K = pa.K[mi], N = pa.N[mi];
    int Npad = (N + 31) & ~31;
    int KB = K >> 3;
    int cells = KB * Npad;
    int cell = blockIdx.x * 256 + threadIdx.x;
    if (cell >= cells) return;
    int nn = cell & 31, r2 = cell >> 5;
    int kblk = r2 % KB, ntile = r2 / KB;
    int n = ntile * 32 + nn;
    const float* W = pa.src[mi];
    half8 v;
#pragma unroll
    for (int j = 0; j < 8; ++j) {
        int k = kblk * 8 + j;
        v[j] = (half_t)((n < N) ? W[k * N + n] : 0.f);
    }
    *reinterpret_cast<half8*>(pa.dst[mi] + (size_t)cell * 8) = v;
}

// =====================================================================
// K1: front: x2b -> lat = cut*mlp(w2b) -> w0 = mlp(env0) -> fs/fv + raw0 scatter.
// =====================================================================
__global__ __launch_bounds__(256) void k_edge_front(
    const float* __restrict__ g_ea, const float* __restrict__ g_na,
    const float* __restrict__ g_emb, const float* __restrict__ g_eu,
    const int* __restrict__ g_eidx,
    const half_t* __restrict__ b_w2b1, const half_t* __restrict__ b_w2b2,
    const half_t* __restrict__ b_e0w1, const half_t* __restrict__ b_e0w2,
    half_t* __restrict__ g_lat0, float* __restrict__ g_fs, float* __restrict__ g_fv,
    float* __restrict__ raw0, int E) {
    __shared__ __align__(16) half_t Ax[2 * 32 * 8];
    __shared__ __align__(16) half_t Al[16 * 32 * 8];
    __shared__ __align__(16) half_t Ah[16 * 32 * 8];
    __shared__ __align__(16) half_t DstH[32 * DS];
    __shared__ float eaS[32 * 4];
    __shared__ float cutS[32];
    __shared__ int cS[32];
    const int t = threadIdx.x, b = blockIdx.x, eb = b * 32;
    const int lane = t & 63, wave = t >> 6;
    const int nl = lane & 31, q = lane >> 5;

    if (t < 32) {
        int e = eb + t;
        cS[t] = g_eidx[e];
        float4 a4 = *reinterpret_cast<const float4*>(g_ea + e * 4);
        eaS[t * 4 + 0] = a4.x; eaS[t * 4 + 1] = a4.y;
        eaS[t * 4 + 2] = a4.z; eaS[t * 4 + 3] = a4.w;
        cutS[t] = poly_cut(g_eu[e]);
    }
    if (t < 64) {
        int kblk = t >> 5, m = t & 31, e = eb + m;
        half8 v;
        if (kblk == 0) {
            int ce = g_eidx[e], ne = g_eidx[E + e];
            float4 nc = *reinterpret_cast<const float4*>(g_na + ce * 4);
            float4 nn = *reinterpret_cast<const float4*>(g_na + ne * 4);
            v[0] = (half_t)nc.x; v[1] = (half_t)nc.y; v[2] = (half_t)nc.z; v[3] = (half_t)nc.w;
            v[4] = (half_t)nn.x; v[5] = (half_t)nn.y; v[6] = (half_t)nn.z; v[7] = (half_t)nn.w;
        } else {
            float4 m0 = *reinterpret_cast<const float4*>(g_emb + e * 8);
            float4 m1 = *reinterpret_cast<const float4*>(g_emb + e * 8 + 4);
            v[0] = (half_t)m0.x; v[1] = (half_t)m0.y; v[2] = (half_t)m0.z; v[3] = (half_t)m0.w;
            v[4] = (half_t)m1.x; v[5] = (half_t)m1.y; v[6] = (half_t)m1.z; v[7] = (half_t)m1.w;
        }
        *reinterpret_cast<half8*>(Ax + t * 8) = v;
    }
    __syncthreads();

    { f32x16 acc = mfma_stage<2>(Ax, b_w2b1, wave, lane); dwrite(DstH, acc, lane, wave * 32); }
    __syncthreads();
    repack_silu(DstH, Ah, t);
    __syncthreads();
    { f32x16 acc = mfma_stage<16>(Ah, b_w2b2, wave, lane); dwrite(DstH, acc, lane, wave * 32); }
    __syncthreads();
    {   // lat = cut * D -> global fp16 (Afrag image) + LDS Al
        half_t* gl = g_lat0 + (size_t)b * 4096;
#pragma unroll
        for (int c = 0; c < 2; ++c) {
            int cell = t + c * 256;
            int kblk = cell >> 5, m = cell & 31;
            half8 s = *reinterpret_cast<const half8*>(DstH + m * DS + kblk * 8);
            float cu = cutS[m];
            half8 v;
#pragma unroll
            for (int j = 0; j < 8; ++j) v[j] = (half_t)(cu * (float)s[j]);
            *reinterpret_cast<half8*>(Al + cell * 8) = v;
            *reinterpret_cast<half8*>(gl + cell * 8) = v;
        }
    }
    __syncthreads();
    { f32x16 acc = mfma_stage<16>(Al, b_e0w1, wave, lane); dwrite(DstH, acc, lane, wave * 32); }
    __syncthreads();
    repack_silu(DstH, Ah, t);
    __syncthreads();
    // e0w2 (N=64): register-direct tail. Lane owns col c, 16 edge-rows.
    if (wave < 2) {
        f32x16 acc = mfma_stage<16>(Ah, b_e0w2, wave, lane);
        int c = wave * 32 + nl;
#pragma unroll
        for (int r = 0; r < 16; ++r) {
            int m = (r & 3) + 8 * (r >> 2) + 4 * q;
            int ge = eb + m;
            float val = acc[r];
            if (c < 32) {
                int u = c >> 1;
                if ((c & 1) == 0) {
                    g_fs[ge * 16 + u] = val * eaS[m * 4 + 0];
                } else {
                    g_fv[ge * 48 + u * 3 + 0] = val * eaS[m * 4 + 1];
                    g_fv[ge * 48 + u * 3 + 1] = val * eaS[m * 4 + 2];
                    g_fv[ge * 48 + u * 3 + 2] = val * eaS[m * 4 + 3];
                }
            } else {
                int u = (c - 32) >> 1;
                int ce = cS[m];
                if ((c & 1) == 0) {
                    atomicAdd(&raw0[ce * 64 + u], val * eaS[m * 4 + 0]);
                } else {
                    atomicAdd(&raw0[ce * 64 + 16 + u * 3 + 0], val * eaS[m * 4 + 1]);
                    atomicAdd(&raw0[ce * 64 + 16 + u * 3 + 1], val * eaS[m * 4 + 2]);
                    atomicAdd(&raw0[ce * 64 + 16 + u * 3 + 2], val * eaS[m * 4 + 3]);
                }
            }
        }
    }
}

// =====================================================================
// K2: per-node env linear (f32).
// =====================================================================
__global__ __launch_bounds__(256) void k_node_lin(
    const float* __restrict__ raw, const float* __restrict__ wls,
    const float* __restrict__ wlv, float* __restrict__ ls, float* __restrict__ lv,
    int Nn) {
    int gid = blockIdx.x * 256 + threadIdx.x;
    if (gid >= Nn * 16) return;
    int n = gid >> 4, v = gid & 15;
    float as = 0.f, a0 = 0.f, a1 = 0.f, a2 = 0.f;
    const float* rp = raw + n * 64;
#pragma unroll
    for (int u = 0; u < 16; ++u) {
        float w1 = wls[u * 16 + v];
        float w2 = wlv[u * 16 + v];
        as = fmaf(rp[u], w1, as);
        a0 = fmaf(rp[16 + u * 3 + 0], w2, a0);
        a1 = fmaf(rp[16 + u * 3 + 1], w2, a1);
        a2 = fmaf(rp[16 + u * 3 + 2], w2, a2);
    }
    ls[n * 16 + v] = as * SC_ENV;
    lv[n * 48 + v * 3 + 0] = a0 * SC_ENV;
    lv[n * 48 + v * 3 + 1] = a1 * SC_ENV;
    lv[n * 48 + v * 3 + 2] = a2 * SC_ENV;
}

// =====================================================================
// K3 (fused): layer-0 tail + register-resident generator fold + layer-1 head.
// =====================================================================
__global__ __launch_bounds__(256) void k_layer0(
    const float* __restrict__ g_ea, const float* __restrict__ g_eu,
    const int* __restrict__ g_eidx,
    float* g_fs, float* g_fv,
    const float* __restrict__ ls0, const float* __restrict__ lv0,
    const half_t* __restrict__ b_lat1w1, const half_t* __restrict__ b_lat1w2,
    const half_t* __restrict__ b_e1w1, const half_t* __restrict__ b_e1w2,
    const half_t* __restrict__ b_gw1, const half_t* __restrict__ b_gw2,
    const half_t* __restrict__ g_lat0, half_t* __restrict__ g_lat1,
    float* __restrict__ raw1, int E) {
    __shared__ __align__(16) half_t Al[20 * 32 * 8];
    __shared__ __align__(16) half_t Ah[16 * 32 * 8];   // also fs/fv f32 staging (8KB)
    __shared__ __align__(16) half_t DstH[32 * DS];     // also fsred/fvred f32 (8KB)
    __shared__ half_t Vsh[32 * VPH];
    __shared__ float eaS[128];
    __shared__ float cutS[32];
    __shared__ int cS[32];
    float* fsred = reinterpret_cast<float*>(DstH);
    float* fvred = fsred + 512;
    float* Ahf = reinterpret_cast<float*>(Ah);
    const int t = threadIdx.x, b = blockIdx.x, eb = b * 32;
    const int lane = t & 63, wave = t >> 6;
    const int nl = lane & 31, q = lane >> 5;
    const half_t* gl0 = g_lat0 + (size_t)b * 4096;

    if (t < 32) {
        int e = eb + t;
        cS[t] = g_eidx[e];
        float4 a4 = *reinterpret_cast<const float4*>(g_ea + e * 4);
        eaS[t * 4 + 0] = a4.x; eaS[t * 4 + 1] = a4.y;
        eaS[t * 4 + 2] = a4.z; eaS[t * 4 + 3] = a4.w;
        cutS[t] = poly_cut(g_eu[e]);
    }
#pragma unroll
    for (int c = 0; c < 2; ++c) {  // latent rows 0..127 (coalesced fp16 copy)
        int cell = t + c * 256;
        *reinterpret_cast<half8*>(Al + cell * 8) =
            *reinterpret_cast<const half8*>(gl0 + cell * 8);
    }
    // coalesced staging of this block's fs (512 f) + fv (1536 f) into Ahf
#pragma unroll
    for (int c = 0; c < 2; ++c) {
        int idx = t + c * 256;
        float4 val = (idx < 128)
                         ? reinterpret_cast<const float4*>(g_fs + (size_t)eb * 16)[idx]
                         : reinterpret_cast<const float4*>(g_fv + (size_t)eb * 48)[idx - 128];
        reinterpret_cast<float4*>(Ahf)[idx] = val;
    }
    __syncthreads();

    // gather env0 -> scalars (Al rows 128..159) + V (fp16 LDS)
#pragma unroll
    for (int p = 0; p < 2; ++p) {
        int item = t + p * 256;
        int m = item >> 5, e = item & 31;
        int ce = cS[e];
        float fs = Ahf[e * 16 + m];
        float fv0 = Ahf[512 + e * 48 + m * 3 + 0];
        float fv1 = Ahf[512 + e * 48 + m * 3 + 1];
        float fv2 = Ahf[512 + e * 48 + m * 3 + 2];
        float es = ls0[ce * 16 + m];
        float ev0 = lv0[ce * 48 + m * 3 + 0];
        float ev1 = lv0[ce * 48 + m * 3 + 1];
        float ev2 = lv0[ce * 48 + m * 3 + 2];
        float s1 = fs * es;
        float s2 = (fv0 * ev0 + fv1 * ev1 + fv2 * ev2) * INV_S3;
        int row = 128 + 2 * m;
        int hidx = ((row >> 3) * 32 + e) * 8 + (row & 7);
        Al[hidx] = (half_t)s1;
        Al[hidx + 1] = (half_t)s2;
        half_t* vp = Vsh + e * VPH;
        vp[m * 3 + 0] = (half_t)(fs * ev0);
        vp[m * 3 + 1] = (half_t)(fs * ev1);
        vp[m * 3 + 2] = (half_t)(fs * ev2);
        vp[48 + m * 3 + 0] = (half_t)(fv0 * es);
        vp[48 + m * 3 + 1] = (half_t)(fv1 * es);
        vp[48 + m * 3 + 2] = (half_t)(fv2 * es);
        vp[96 + m * 3 + 0] = (half_t)((fv1 * ev2 - fv2 * ev1) * INV_S2);
        vp[96 + m * 3 + 1] = (half_t)((fv2 * ev0 - fv0 * ev2) * INV_S2);
        vp[96 + m * 3 + 2] = (half_t)((fv0 * ev1 - fv1 * ev0) * INV_S2);
    }
    __syncthreads();

    // h = silu(latent0 @ gw1)
    { f32x16 acc = mfma_stage<20>(Al, b_gw1, wave, lane); dwrite(DstH, acc, lane, wave * 32); }
    __syncthreads();
    repack_silu(DstH, Ah, t);
    __syncthreads();
    // zero fold accumulators (alias DstH; DstH dead after repack)
#pragma unroll
    for (int j = 0; j < 8; ++j) fsred[t + j * 256] = 0.f;
    __syncthreads();

    // ---- register-resident fold: chunks 0..3 = ws part ----
    {
        float fsacc[16];
#pragma unroll
        for (int r = 0; r < 16; ++r) fsacc[r] = 0.f;
#pragma unroll 2
        for (int chunk = 0; chunk < 4; ++chunk) {
            f32x16 acc = mfma_stage<16>(Ah, b_gw2, chunk * 4 + wave, lane);
            int c = chunk * 128 + wave * 32 + nl;
            int pu = c >> 4;
            int row = 128 + 2 * (pu & 15) + (pu >> 4);
            int hbase = ((row >> 3) * 32) * 8 + (row & 7);
#pragma unroll
            for (int r = 0; r < 16; ++r) {
                int m = (r & 3) + 8 * (r >> 2) + 4 * q;
                float s = (float)Al[hbase + m * 8];  // wave-broadcast
                fsacc[r] = fmaf(s, acc[r], fsacc[r]);
            }
        }
        int v = nl & 15;
#pragma unroll
        for (int r = 0; r < 16; ++r) {
            int m = (r & 3) + 8 * (r >> 2) + 4 * q;
            atomicAdd(&fsred[m * 16 + v], fsacc[r]);
        }
    }
    // ---- chunks 4..9 = wv part ----
    {
        float fvacc[16][3];
#pragma unroll
        for (int r = 0; r < 16; ++r) fvacc[r][0] = fvacc[r][1] = fvacc[r][2] = 0.f;
#pragma unroll 2
        for (int chunk = 4; chunk < 10; ++chunk) {
            f32x16 acc = mfma_stage<16>(Ah, b_gw2, chunk * 4 + wave, lane);
            int c2 = chunk * 128 + wave * 32 + nl - 512;
            int off = (c2 >> 4) * 3;
#pragma unroll
            for (int r = 0; r < 16; ++r) {
                int m = (r & 3) + 8 * (r >> 2) + 4 * q;
                float v0 = (float)Vsh[m * VPH + off + 0];
                float v1 = (float)Vsh[m * VPH + off + 1];
                float v2 = (float)Vsh[m * VPH + off + 2];
                fvacc[r][0] = fmaf(v0, acc[r], fvacc[r][0]);
                fvacc[r][1] = fmaf(v1, acc[r], fvacc[r][1]);
                fvacc[r][2] = fmaf(v2, acc[r], fvacc[r][2]);
            }
        }
        int v = nl & 15;
#pragma unroll
        for (int r = 0; r < 16; ++r) {
            int m = (r & 3) + 8 * (r >> 2) + 4 * q;
            atomicAdd(&fvred[m * 48 + v * 3 + 0], fvacc[r][0]);
            atomicAdd(&fvred[m * 48 + v * 3 + 1], fvacc[r][1]);
            atomicAdd(&fvred[m * 48 + v * 3 + 2], fvacc[r][2]);
        }
    }
    __syncthreads();
#pragma unroll
    for (int j = 0; j < 2; ++j) g_fs[eb * 16 + t + j * 256] = fsred[t + j * 256] * SC_FS;
#pragma unroll
    for (int j = 0; j < 6; ++j) g_fv[eb * 48 + t + j * 256] = fvred[t + j * 256] * SC_FV;
    __syncthreads();  // fsred/fvred reads done before DstH reuse

    // latent update: h2 = silu(latent_in @ lat1w1); new = h2 @ lat1w2
    { f32x16 acc = mfma_stage<20>(Al, b_lat1w1, wave, lane); dwrite(DstH, acc, lane, wave * 32); }
    __syncthreads();
    repack_silu(DstH, Ah, t);
    __syncthreads();
    { f32x16 acc = mfma_stage<16>(Ah, b_lat1w2, wave, lane); dwrite(DstH, acc, lane, wave * 32); }
    __syncthreads();
    {   // lat' = C_OLD*lat + A_COLD*cut*new -> g_lat1 + Al rows 0..127
        half_t* gl1 = g_lat1 + (size_t)b * 4096;
#pragma unroll
        for (int c = 0; c < 2; ++c) {
            int cell = t + c * 256;
            int kblk = cell >> 5, m = cell & 31;
            half8 s = *reinterpret_cast<const half8*>(DstH + m * DS + kblk * 8);
            half8 op = *reinterpret_cast<const half8*>(Al + cell * 8);
            float cu = cutS[m];
            half8 v;
#pragma unroll
            for (int j = 0; j < 8; ++j) {
                float x = C_OLD * (float)op[j] + A_COLD * cu * (float)s[j];
                v[j] = (half_t)x;
            }
            *reinterpret_cast<half8*>(Al + cell * 8) = v;
            *reinterpret_cast<half8*>(gl1 + cell * 8) = v;
        }
    }
    __syncthreads();
    // w_env = mlp(lat', env1)
    { f32x16 acc = mfma_stage<16>(Al, b_e1w1, wave, lane); dwrite(DstH, acc, lane, wave * 32); }
    __syncthreads();
    repack_silu(DstH, Ah, t);
    __syncthreads();
    // e1w2 (N=32): wave0 register-direct scatter
    if (wave == 0) {
        f32x16 acc = mfma_stage<16>(Ah, b_e1w2, 0, lane);
        int u = nl >> 1;
#pragma unroll
        for (int r = 0; r < 16; ++r) {
            int m = (r & 3) + 8 * (r >> 2) + 4 * q;
            int ce = cS[m];
            float val = acc[r];
            if ((nl & 1) == 0) {
                atomicAdd(&raw1[ce * 64 + u], val * eaS[m * 4 + 0]);
            } else {
                atomicAdd(&raw1[ce * 64 + 16 + u * 3 + 0], val * eaS[m * 4 + 1]);
                atomicAdd(&raw1[ce * 64 + 16 + u * 3 + 1], val * eaS[m * 4 + 2]);
                atomicAdd(&raw1[ce * 64 + 16 + u * 3 + 2], val * eaS[m * 4 + 3]);
            }
        }
    }
}

// =====================================================================
// K5 (fused): layer-1 gather + fw MLP + register fold (wv) + output.
// =====================================================================
__global__ __launch_bounds__(256) void k_layer1(
    const int* __restrict__ g_eidx, const float* __restrict__ g_fs,
    const float* __restrict__ g_fv, const float* __restrict__ ls1,
    const float* __restrict__ lv1,
    const half_t* __restrict__ b_flw1, const half_t* __restrict__ b_flw2,
    const half_t* __restrict__ b_gw1, const half_t* __restrict__ b_gw2,
    const half_t* __restrict__ g_lat1, float* __restrict__ g_out, int E) {
    __shared__ __align__(16) half_t Al[20 * 32 * 8];
    __shared__ __align__(16) half_t Ah[16 * 32 * 8];   // also fs/fv f32 staging
    __shared__ __align__(16) half_t DstH[32 * DS];     // also fvred f32 (6KB)
    __shared__ half_t Vsh[32 * VPH];
    __shared__ float fwS[512];
    __shared__ int cS[32];
    float* fvred = reinterpret_cast<float*>(DstH);
    float* Ahf = reinterpret_cast<float*>(Ah);
    const int t = threadIdx.x, b = blockIdx.x, eb = b * 32;
    const int lane = t & 63, wave = t >> 6;
    const int nl = lane & 31, q = lane >> 5;
    const half_t* gl1 = g_lat1 + (size_t)b * 4096;

    if (t < 32) cS[t] = g_eidx[eb + t];
#pragma unroll
    for (int c = 0; c < 2; ++c) {
        int cell = t + c * 256;
        *reinterpret_cast<half8*>(Al + cell * 8) =
            *reinterpret_cast<const half8*>(gl1 + cell * 8);
    }
#pragma unroll
    for (int c = 0; c < 2; ++c) {
        int idx = t + c * 256;
        float4 val = (idx < 128)
                         ? reinterpret_cast<const float4*>(g_fs + (size_t)eb * 16)[idx]
                         : reinterpret_cast<const float4*>(g_fv + (size_t)eb * 48)[idx - 128];
        reinterpret_cast<float4*>(Ahf)[idx] = val;
    }
    __syncthreads();

#pragma unroll
    for (int p = 0; p < 2; ++p) {
        int item = t + p * 256;
        int m = item >> 5, e = item & 31;
        int ce = cS[e];
        float fs = Ahf[e * 16 + m];
        float fv0 = Ahf[512 + e * 48 + m * 3 + 0];
        float fv1 = Ahf[512 + e * 48 + m * 3 + 1];
        float fv2 = Ahf[512 + e * 48 + m * 3 + 2];
        float es = ls1[ce * 16 + m];
        float ev0 = lv1[ce * 48 + m * 3 + 0];
        float ev1 = lv1[ce * 48 + m * 3 + 1];
        float ev2 = lv1[ce * 48 + m * 3 + 2];
        float s1 = fs * es;
        float s2 = (fv0 * ev0 + fv1 * ev1 + fv2 * ev2) * INV_S3;
        int row = 128 + 2 * m;
        int hidx = ((row >> 3) * 32 + e) * 8 + (row & 7);
        Al[hidx] = (half_t)s1;
        Al[hidx + 1] = (half_t)s2;
        half_t* vp = Vsh + e * VPH;
        vp[m * 3 + 0] = (half_t)(fs * ev0);
        vp[m * 3 + 1] = (half_t)(fs * ev1);
        vp[m * 3 + 2] = (half_t)(fs * ev2);
        vp[48 + m * 3 + 0] = (half_t)(fv0 * es);
        vp[48 + m * 3 + 1] = (half_t)(fv1 * es);
        vp[48 + m * 3 + 2] = (half_t)(fv2 * es);
        vp[96 + m * 3 + 0] = (half_t)((fv1 * ev2 - fv2 * ev1) * INV_S2);
        vp[96 + m * 3 + 1] = (half_t)((fv2 * ev0 - fv0 * ev2) * INV_S2);
        vp[96 + m * 3 + 2] = (half_t)((fv0 * ev1 - fv1 * ev0) * INV_S2);
    }
    __syncthreads();

    // fw = mlp(latent1, fl2w)
    { f32x16 acc = mfma_stage<20>(Al, b_flw1, wave, lane); dwrite(DstH, acc, lane, wave * 32); }
    __syncthreads();
    repack_silu(DstH, Ah, t);
    __syncthreads();
    // flw2 (N=16): wave0 register-direct -> fwS
    if (wave == 0) {
        f32x16 acc = mfma_stage<16>(Ah, b_flw2, 0, lane);
        if (nl < 16) {
#pragma unroll
            for (int r = 0; r < 16; ++r) {
                int m = (r & 3) + 8 * (r >> 2) + 4 * q;
                fwS[m * 16 + nl] = acc[r];
            }
        }
    }
    // h = silu(latent1 @ gw1)  (DstH free after the repack above)
    { f32x16 acc = mfma_stage<20>(Al, b_gw1, wave, lane); dwrite(DstH, acc, lane, wave * 32); }
    __syncthreads();
    repack_silu(DstH, Ah, t);
    __syncthreads();
#pragma unroll
    for (int j = 0; j < 6; ++j) fvred[t + j * 256] = 0.f;  // zero fvred (alias)
    __syncthreads();

    // register fold: chunks 4..9 (wv part)
    {
        float fvacc[16][3];
#pragma unroll
        for (int r = 0; r < 16; ++r) fvacc[r][0] = fvacc[r][1] = fvacc[r][2] = 0.f;
#pragma unroll 2
        for (int chunk = 4; chunk < 10; ++chunk) {
            f32x16 acc = mfma_stage<16>(Ah, b_gw2, chunk * 4 + wave, lane);
            int c2 = chunk * 128 + wave * 32 + nl - 512;
            int off = (c2 >> 4) * 3;
#pragma unroll
            for (int r = 0; r < 16; ++r) {
                int m = (r & 3) + 8 * (r >> 2) + 4 * q;
                float v0 = (float)Vsh[m * VPH + off + 0];
                float v1 = (float)Vsh[m * VPH + off + 1];
                float v2 = (float)Vsh[m * VPH + off + 2];
                fvacc[r][0] = fmaf(v0, acc[r], fvacc[r][0]);
                fvacc[r][1] = fmaf(v1, acc[r], fvacc[r][1]);
                fvacc[r][2] = fmaf(v2, acc[r], fvacc[r][2]);
            }
        }
        int v = nl & 15;
#pragma unroll
        for (int r = 0; r < 16; ++r) {
            int m = (r & 3) + 8 * (r >> 2) + 4 * q;
            atomicAdd(&fvred[m * 48 + v * 3 + 0], fvacc[r][0]);
            atomicAdd(&fvred[m * 48 + v * 3 + 1], fvacc[r][1]);
            atomicAdd(&fvred[m * 48 + v * 3 + 2], fvacc[r][2]);
        }
    }
    __syncthreads();
    if (t < 96) {
        int e = t / 3, i = t % 3;
        const float* fwp = fwS + e * 16;
        const float* fr = fvred + e * 48 + i;
        float o = 0.f;
#pragma unroll
        for (int u = 0; u < 16; ++u) o = fmaf(fwp[u], fr[u * 3], o);
        g_out[(eb + e) * 3 + i] = o * SC_OUT;
    }
}

// =====================================================================
extern "C" void kernel_launch(void* const* d_in, const int* in_sizes, int n_in,
                              void* d_out, int out_size, void* d_ws, size_t ws_size,
                              hipStream_t stream) {
    const float* g_ea = (const float*)d_in[0];
    const float* g_na = (const float*)d_in[1];
    const float* g_emb = (const float*)d_in[2];
    const float* g_eu = (const float*)d_in[3];
    const int* g_eidx = (const int*)d_in[4];
    const float* w2b1 = (const float*)d_in[5];
    const float* w2b2 = (const float*)d_in[6];
    const float* lat1w1 = (const float*)d_in[7];
    const float* lat1w2 = (const float*)d_in[8];
    const float* e0w1 = (const float*)d_in[9];
    const float* e0w2 = (const float*)d_in[10];
    const float* e1w1 = (const float*)d_in[11];
    const float* e1w2 = (const float*)d_in[12];
    const float* l2w0w1 = (const float*)d_in[13];
    const float* l2w0w2 = (const float*)d_in[14];
    const float* l2w1w1 = (const float*)d_in[15];
    const float* l2w1w2 = (const float*)d_in[16];
    const float* envws = (const float*)d_in[17];
    const float* envwv = (const float*)d_in[18];
    const float* flw1 = (const float*)d_in[19];
    const float* flw2 = (const float*)d_in[20];
    float* out = (float*)d_out;

    const int E = in_sizes[3];       // 120000
    const int Nn = in_sizes[1] / 4;  // 5000
    const int nblk = E / 32;         // 3750

    float* p = (float*)d_ws;
    float* gfs = p;  p += (size_t)E * 16;
    float* gfv = p;  p += (size_t)E * 48;
    float* raw0 = p; p += (size_t)Nn * 64;
    float* raw1 = p; p += (size_t)Nn * 64;
    float* ls0 = p;  p += (size_t)Nn * 16;
    float* lv0 = p;  p += (size_t)Nn * 48;
    float* ls1 = p;  p += (size_t)Nn * 16;
    float* lv1 = p;  p += (size_t)Nn * 48;
    half_t* hp = (half_t*)p;
    half_t* lat0h = hp; hp += (size_t)nblk * 4096;
    half_t* lat1h = hp; hp += (size_t)nblk * 4096;

    const int KN[14][2] = {{16, 128}, {128, 128}, {128, 128}, {128, 64},
                           {160, 128}, {128, 128}, {128, 128}, {128, 32},
                           {160, 128}, {128, 1280}, {160, 128}, {128, 1280},
                           {160, 128}, {128, 16}};
    const float* srcs[14] = {w2b1, w2b2, e0w1, e0w2, lat1w1, lat1w2, e1w1, e1w2,
                             l2w0w1, l2w0w2, l2w1w1, l2w1w2, flw1, flw2};
    PackArgs pa;
    half_t* bptr[14];
    for (int i = 0; i < 14; ++i) {
        int K = KN[i][0], N = KN[i][1];
        int Npad = (N + 31) & ~31;
        bptr[i] = hp;
        hp += (size_t)K * Npad;
        pa.src[i] = srcs[i];
        pa.dst[i] = bptr[i];
        pa.K[i] = K;
        pa.N[i] = N;
    }

    k_pack<<<dim3(80, 14), 256, 0, stream>>>(pa);

    const int nzero = Nn * 128;
    k_zero<<<(nzero + 255) / 256, 256, 0, stream>>>(raw0, nzero);

    const int nb2 = (Nn * 16 + 255) / 256;

    k_edge_front<<<nblk, 256, 0, stream>>>(g_ea, g_na, g_emb, g_eu, g_eidx,
                                           bptr[0], bptr[1], bptr[2], bptr[3],
                                           lat0h, gfs, gfv, raw0, E);
    k_node_lin<<<nb2, 256, 0, stream>>>(raw0, envws, envwv, ls0, lv0, Nn);
    k_layer0<<<nblk, 256, 0, stream>>>(g_ea, g_eu, g_eidx, gfs, gfv, ls0, lv0,
                                       bptr[4], bptr[5], bptr[6], bptr[7],
                                       bptr[8], bptr[9], lat0h, lat1h, raw1, E);
    k_node_lin<<<nb2, 256, 0, stream>>>(raw1, envws + 256, envwv + 256, ls1, lv1, Nn);
    k_layer1<<<nblk, 256, 0, stream>>>(g_eidx, gfs, gfv, ls1, lv1,
                                       bptr[12], bptr[13], bptr[10], bptr[11],
                                       lat1h, out, E);
}

// Round 7
// 917.246 us; speedup vs baseline: 1.4053x; 1.4053x over previous
//
#include <hip/hip_runtime.h>

typedef _Float16 half_t;
typedef _Float16 half8 __attribute__((ext_vector_type(8)));
typedef _Float16 half2_t __attribute__((ext_vector_type(2)));
typedef float f32x16 __attribute__((ext_vector_type(16)));
typedef float f32x4 __attribute__((ext_vector_type(4)));

#define DEVINL __device__ __forceinline__

// ---------- constants ----------
#define INV_S3 0.57735026918962576f   // 1/sqrt(3)
#define INV_S2 0.70710678118654752f   // 1/sqrt(2)
#define C_OLD  0.89442719099991588f   // 1/sqrt(1.25)
#define A_COLD 0.44721359549995794f   // 0.5/sqrt(1.25)
#define SC_ENV 0.05590169943749474f   // (1/sqrt(20)) * (1/4)
#define SC_FS  0.17677669529663688f   // 1/sqrt(32)
#define SC_FV  0.14433756729740643f   // 1/sqrt(48)
#define SC_OUT 0.03608439182435161f   // (1/4)/sqrt(48)
#define SSD 34                         // sS stride (halfs)
#define VPH 146                        // V stride (halfs)

DEVINL float silu_f(float x) { return x / (1.f + __expf(-x)); }

DEVINL float poly_cut(float u) {
    float u2 = u * u, u4 = u2 * u2, u6 = u4 * u2;
    float f = 1.f - 28.f * u6 + 48.f * u6 * u - 21.f * u6 * u2;
    return (u < 1.f) ? f : 0.f;
}

DEVINL float pkh(float a, float b) {  // pack 2 f32 -> half2 bits in a float (RNE)
    half2_t h; h[0] = (half_t)a; h[1] = (half_t)b;
    return __builtin_bit_cast(float, h);
}
DEVINL float2 uph(float p) {
    half2_t h = __builtin_bit_cast(half2_t, p);
    return make_float2((float)h[0], (float)h[1]);
}
DEVINL half8 mk8(const float* w) {
    f32x4 v = {w[0], w[1], w[2], w[3]};
    return __builtin_bit_cast(half8, v);
}
// type-safe: read two adjacent LDS halfs, return packed-as-float (no aliasing UB)
DEVINL float ld_pk2(const half_t* p) {
    half2_t h; h[0] = p[0]; h[1] = p[1];
    return __builtin_bit_cast(float, h);
}

// =====================================================================
// Edge-column MFMA stage: A = weights [M=features], B = edges (in regs).
// Weight pack: cell(mtile,kblk,m) at halfs[((mtile*KB+kblk)*32+m)*8+j]
// B windows: 4 packed floats per 16-k window; lane (n + 32q) holds k = 8q+j.
// D: lane owns edge col n = lane&31; row f = (r&3) + 8*(r>>2) + 4*(lane>>5).
// =====================================================================
template <int KB>  // K/8
DEVINL f32x16 colstage(const half_t* __restrict__ Wg, const float* B, int mtile,
                       int nl, int q) {
    const half_t* ap = Wg + (((size_t)mtile * KB + q) * 32 + nl) * 8;
    f32x16 acc;
#pragma unroll
    for (int i = 0; i < 16; ++i) acc[i] = 0.f;
#pragma unroll
    for (int h = 0; h < KB / 2; ++h) {
        half8 a = *reinterpret_cast<const half8*>(ap + h * 512);
        acc = __builtin_amdgcn_mfma_f32_32x32x16_f16(a, mk8(B + h * 4), acc, 0, 0, 0);
    }
    return acc;
}

DEVINL void silu16(f32x16& a) {
#pragma unroll
    for (int i = 0; i < 16; ++i) a[i] = silu_f(a[i]);
}

// D (f32 regs) -> B-frag for next stage: two k-windows of 4 packed floats.
// Half-wave exchange via __shfl(lane^32) — no LDS, no barrier.
DEVINL void d2b(const f32x16& d, int lane, int q, float* wA, float* wB) {
    float pk[8];
#pragma unroll
    for (int a2 = 0; a2 < 4; ++a2) {
        pk[a2 * 2 + 0] = pkh(d[4 * a2 + 0], d[4 * a2 + 1]);
        pk[a2 * 2 + 1] = pkh(d[4 * a2 + 2], d[4 * a2 + 3]);
    }
#pragma unroll
    for (int t = 0; t < 2; ++t) {
        float k0 = q ? pk[(2 * t + 1) * 2 + 0] : pk[(2 * t) * 2 + 0];
        float k1 = q ? pk[(2 * t + 1) * 2 + 1] : pk[(2 * t) * 2 + 1];
        float s0 = q ? pk[(2 * t) * 2 + 0] : pk[(2 * t + 1) * 2 + 0];
        float s1 = q ? pk[(2 * t) * 2 + 1] : pk[(2 * t + 1) * 2 + 1];
        float r0 = __shfl(s0, lane ^ 32, 64);
        float r1 = __shfl(s1, lane ^ 32, 64);
        float* w = t ? wB : wA;
        w[0] = q ? r0 : k0;
        w[1] = q ? r1 : k1;
        w[2] = q ? k0 : r0;
        w[3] = q ? k1 : r1;
    }
}

// =====================================================================
__global__ __launch_bounds__(256) void k_zero(float* __restrict__ p, int n) {
    int i = blockIdx.x * 256 + threadIdx.x;
    if (i < n) p[i] = 0.f;
}

// =====================================================================
// Weight pack: f32 [K][N] row-major -> fp16 fragment layout (N padded to 32).
// =====================================================================
struct PackArgs {
    const float* src[14];
    half_t* dst[14];
    int K[14];
    int N[14];
};

__global__ __launch_bounds__(256) void k_pack(PackArgs pa) {
    int mi = blockIdx.y;
    int K = pa.K[mi], N = pa.N[mi];
    int Npad = (N + 31) & ~31;
    int KB = K >> 3;
    int cells = KB * Npad;
    int cell = blockIdx.x * 256 + threadIdx.x;
    if (cell >= cells) return;
    int nn = cell & 31, r2 = cell >> 5;
    int kblk = r2 % KB, ntile = r2 / KB;
    int n = ntile * 32 + nn;
    const float* W = pa.src[mi];
    half8 v;
#pragma unroll
    for (int j = 0; j < 8; ++j) {
        int k = kblk * 8 + j;
        v[j] = (half_t)((n < N) ? W[k * N + n] : 0.f);
    }
    *reinterpret_cast<half8*>(pa.dst[mi] + (size_t)cell * 8) = v;
}

// =====================================================================
// K1: front. One wave per 32 edges, barrier-free (no LDS).
// =====================================================================
__global__ __launch_bounds__(64, 3) void k_edge_front(
    const float* __restrict__ g_ea, const float* __restrict__ g_na,
    const float* __restrict__ g_emb, const float* __restrict__ g_eu,
    const int* __restrict__ g_eidx,
    const half_t* __restrict__ b_w2b1, const half_t* __restrict__ b_w2b2,
    const half_t* __restrict__ b_e0w1, const half_t* __restrict__ b_e0w2,
    half_t* __restrict__ g_lat0, float* __restrict__ g_fs, float* __restrict__ g_fv,
    float* __restrict__ raw0, int E) {
    const int lane = threadIdx.x, nl = lane & 31, q = lane >> 5;
    const int b = blockIdx.x, eb = b * 32, e = eb + nl;
    int ce = g_eidx[e];
    float4 ea = *reinterpret_cast<const float4*>(g_ea + e * 4);
    float cut = poly_cut(g_eu[e]);

    float xw[4];
    if (q == 0) {
        int ne = g_eidx[E + e];
        float4 nc = *reinterpret_cast<const float4*>(g_na + ce * 4);
        float4 nn = *reinterpret_cast<const float4*>(g_na + ne * 4);
        xw[0] = pkh(nc.x, nc.y); xw[1] = pkh(nc.z, nc.w);
        xw[2] = pkh(nn.x, nn.y); xw[3] = pkh(nn.z, nn.w);
    } else {
        float4 m0 = *reinterpret_cast<const float4*>(g_emb + e * 8);
        float4 m1 = *reinterpret_cast<const float4*>(g_emb + e * 8 + 4);
        xw[0] = pkh(m0.x, m0.y); xw[1] = pkh(m0.z, m0.w);
        xw[2] = pkh(m1.x, m1.y); xw[3] = pkh(m1.z, m1.w);
    }

    float hB[32], lB[32];
#pragma unroll
    for (int c = 0; c < 4; ++c) {  // w2b1: K=16
        f32x16 d = colstage<2>(b_w2b1, xw, c, nl, q);
        silu16(d);
        d2b(d, lane, q, &hB[8 * c], &hB[8 * c + 4]);
    }
    half_t* gl = g_lat0 + (size_t)b * 4096;
#pragma unroll
    for (int c = 0; c < 4; ++c) {  // w2b2 -> lat = cut*D
        f32x16 d = colstage<16>(b_w2b2, hB, c, nl, q);
#pragma unroll
        for (int i = 0; i < 16; ++i) d[i] *= cut;
        d2b(d, lane, q, &lB[8 * c], &lB[8 * c + 4]);
        *reinterpret_cast<half8*>(gl + ((4 * c + q) * 32 + nl) * 8) = mk8(&lB[8 * c]);
        *reinterpret_cast<half8*>(gl + ((4 * c + 2 + q) * 32 + nl) * 8) = mk8(&lB[8 * c + 4]);
    }
#pragma unroll
    for (int c = 0; c < 4; ++c) {  // e0w1
        f32x16 d = colstage<16>(b_e0w1, lB, c, nl, q);
        silu16(d);
        d2b(d, lane, q, &hB[8 * c], &hB[8 * c + 4]);
    }
    {  // e0w2 mtile0: fs/fv
        f32x16 d = colstage<16>(b_e0w2, hB, 0, nl, q);
#pragma unroll
        for (int r = 0; r < 16; ++r) {
            int f = (r & 3) + 8 * (r >> 2) + 4 * q;
            int u = f >> 1;
            float val = d[r];
            if ((f & 1) == 0) {
                g_fs[e * 16 + u] = val * ea.x;
            } else {
                g_fv[e * 48 + u * 3 + 0] = val * ea.y;
                g_fv[e * 48 + u * 3 + 1] = val * ea.z;
                g_fv[e * 48 + u * 3 + 2] = val * ea.w;
            }
        }
    }
    {  // e0w2 mtile1: raw0 scatter
        f32x16 d = colstage<16>(b_e0w2, hB, 1, nl, q);
#pragma unroll
        for (int r = 0; r < 16; ++r) {
            int f = (r & 3) + 8 * (r >> 2) + 4 * q;
            int u = f >> 1;
            float val = d[r];
            if ((f & 1) == 0) {
                atomicAdd(&raw0[ce * 64 + u], val * ea.x);
            } else {
                atomicAdd(&raw0[ce * 64 + 16 + u * 3 + 0], val * ea.y);
                atomicAdd(&raw0[ce * 64 + 16 + u * 3 + 1], val * ea.z);
                atomicAdd(&raw0[ce * 64 + 16 + u * 3 + 2], val * ea.w);
            }
        }
    }
}

// =====================================================================
// K2: per-node env linear (f32).
// =====================================================================
__global__ __launch_bounds__(256) void k_node_lin(
    const float* __restrict__ raw, const float* __restrict__ wls,
    const float* __restrict__ wlv, float* __restrict__ ls, float* __restrict__ lv,
    int Nn) {
    int gid = blockIdx.x * 256 + threadIdx.x;
    if (gid >= Nn * 16) return;
    int n = gid >> 4, v = gid & 15;
    float as = 0.f, a0 = 0.f, a1 = 0.f, a2 = 0.f;
    const float* rp = raw + n * 64;
#pragma unroll
    for (int u = 0; u < 16; ++u) {
        float w1 = wls[u * 16 + v];
        float w2 = wlv[u * 16 + v];
        as = fmaf(rp[u], w1, as);
        a0 = fmaf(rp[16 + u * 3 + 0], w2, a0);
        a1 = fmaf(rp[16 + u * 3 + 1], w2, a1);
        a2 = fmaf(rp[16 + u * 3 + 2], w2, a2);
    }
    ls[n * 16 + v] = as * SC_ENV;
    lv[n * 48 + v * 3 + 0] = a0 * SC_ENV;
    lv[n * 48 + v * 3 + 1] = a1 * SC_ENV;
    lv[n * 48 + v * 3 + 2] = a2 * SC_ENV;
}

// =====================================================================
// K3: layer0 — gather, fold (per-lane private), latent update, env1 scatter.
// =====================================================================
__global__ __launch_bounds__(64, 3) void k_layer0(
    const float* __restrict__ g_ea, const float* __restrict__ g_eu,
    const int* __restrict__ g_eidx,
    float* g_fs, float* g_fv,
    const float* __restrict__ ls0, const float* __restrict__ lv0,
    const half_t* __restrict__ b_lat1w1, const half_t* __restrict__ b_lat1w2,
    const half_t* __restrict__ b_e1w1, const half_t* __restrict__ b_e1w2,
    const half_t* __restrict__ b_gw1, const half_t* __restrict__ b_gw2,
    const half_t* __restrict__ g_lat0, half_t* __restrict__ g_lat1,
    float* __restrict__ raw1, int E) {
    __shared__ half_t sS[32 * SSD];
    __shared__ half_t Vsh[32 * VPH];
    const int lane = threadIdx.x, nl = lane & 31, q = lane >> 5;
    const int b = blockIdx.x, eb = b * 32, e = eb + nl;
    int ce = g_eidx[e];
    float4 ea = *reinterpret_cast<const float4*>(g_ea + e * 4);
    float cut = poly_cut(g_eu[e]);

    float lB[40];
    const half_t* gl0 = g_lat0 + (size_t)b * 4096;
#pragma unroll
    for (int h = 0; h < 8; ++h) {
        f32x4 v = *reinterpret_cast<const f32x4*>(gl0 + ((2 * h + q) * 32 + nl) * 8);
        lB[h * 4 + 0] = v[0]; lB[h * 4 + 1] = v[1];
        lB[h * 4 + 2] = v[2]; lB[h * 4 + 3] = v[3];
    }
    // gather env0: lane handles its edge, m = 8q..8q+7
#pragma unroll
    for (int mm = 0; mm < 8; ++mm) {
        int m = q * 8 + mm;
        float fs = g_fs[e * 16 + m];
        float fv0 = g_fv[e * 48 + m * 3 + 0];
        float fv1 = g_fv[e * 48 + m * 3 + 1];
        float fv2 = g_fv[e * 48 + m * 3 + 2];
        float es = ls0[ce * 16 + m];
        float ev0 = lv0[ce * 48 + m * 3 + 0];
        float ev1 = lv0[ce * 48 + m * 3 + 1];
        float ev2 = lv0[ce * 48 + m * 3 + 2];
        float s1 = fs * es;
        float s2 = (fv0 * ev0 + fv1 * ev1 + fv2 * ev2) * INV_S3;
        sS[nl * SSD + 2 * m + 0] = (half_t)s1;
        sS[nl * SSD + 2 * m + 1] = (half_t)s2;
        half_t* vp = Vsh + nl * VPH;
        vp[m * 3 + 0] = (half_t)(fs * ev0);
        vp[m * 3 + 1] = (half_t)(fs * ev1);
        vp[m * 3 + 2] = (half_t)(fs * ev2);
        vp[(16 + m) * 3 + 0] = (half_t)(fv0 * es);
        vp[(16 + m) * 3 + 1] = (half_t)(fv1 * es);
        vp[(16 + m) * 3 + 2] = (half_t)(fv2 * es);
        vp[(32 + m) * 3 + 0] = (half_t)((fv1 * ev2 - fv2 * ev1) * INV_S2);
        vp[(32 + m) * 3 + 1] = (half_t)((fv2 * ev0 - fv0 * ev2) * INV_S2);
        vp[(32 + m) * 3 + 2] = (half_t)((fv0 * ev1 - fv1 * ev0) * INV_S2);
    }
    __syncthreads();  // LDS producer->consumer join (also compiler fence)

    // latent windows 8,9 (scalars) — type-safe half reads
#pragma unroll
    for (int j2 = 0; j2 < 4; ++j2) {
        lB[32 + j2] = ld_pk2(sS + nl * SSD + 8 * q + 2 * j2);
        lB[36 + j2] = ld_pk2(sS + nl * SSD + 16 + 8 * q + 2 * j2);
    }

    float hB[32];
#pragma unroll
    for (int c = 0; c < 4; ++c) {  // gw1
        f32x16 d = colstage<20>(b_gw1, lB, c, nl, q);
        silu16(d);
        d2b(d, lane, q, &hB[8 * c], &hB[8 * c + 4]);
    }
    {  // gw2 ws fold: mtiles 0..15, per-lane private accumulation
        float fsacc[8];
#pragma unroll
        for (int s = 0; s < 8; ++s) fsacc[s] = 0.f;
        for (int c = 0; c < 16; ++c) {
            f32x16 d = colstage<16>(b_gw2, hB, c, nl, q);
            int pu0 = 2 * c, pu1 = 2 * c + 1;
            float S0 = (float)sS[nl * SSD + 2 * (pu0 & 15) + (pu0 >> 4)];
            float S1 = (float)sS[nl * SSD + 2 * (pu1 & 15) + (pu1 >> 4)];
#pragma unroll
            for (int r = 0; r < 16; ++r) {
                int a = r >> 2, bb = r & 3, slot = (a & 1) * 4 + bb;
                fsacc[slot] = fmaf((a < 2) ? S0 : S1, d[r], fsacc[slot]);
            }
        }
#pragma unroll
        for (int s = 0; s < 8; ++s) {
            int v = (s & 3) + 4 * q + 8 * (s >> 2);
            g_fs[e * 16 + v] = fsacc[s] * SC_FS;
        }
    }
    {  // gw2 wv fold: mtiles 16..39
        float fvacc[8][3];
#pragma unroll
        for (int s = 0; s < 8; ++s) fvacc[s][0] = fvacc[s][1] = fvacc[s][2] = 0.f;
        for (int c = 16; c < 40; ++c) {
            f32x16 d = colstage<16>(b_gw2, hB, c, nl, q);
            int w0 = 2 * c - 32, w1 = 2 * c - 31;
            const half_t* vp = Vsh + nl * VPH;
            float V00 = (float)vp[w0 * 3], V01 = (float)vp[w0 * 3 + 1], V02 = (float)vp[w0 * 3 + 2];
            float V10 = (float)vp[w1 * 3], V11 = (float)vp[w1 * 3 + 1], V12 = (float)vp[w1 * 3 + 2];
#pragma unroll
            for (int r = 0; r < 16; ++r) {
                int a = r >> 2, bb = r & 3, slot = (a & 1) * 4 + bb;
                float x0 = (a < 2) ? V00 : V10;
                float x1 = (a < 2) ? V01 : V11;
                float x2 = (a < 2) ? V02 : V12;
                fvacc[slot][0] = fmaf(x0, d[r], fvacc[slot][0]);
                fvacc[slot][1] = fmaf(x1, d[r], fvacc[slot][1]);
                fvacc[slot][2] = fmaf(x2, d[r], fvacc[slot][2]);
            }
        }
#pragma unroll
        for (int s = 0; s < 8; ++s) {
            int v = (s & 3) + 4 * q + 8 * (s >> 2);
            g_fv[e * 48 + v * 3 + 0] = fvacc[s][0] * SC_FV;
            g_fv[e * 48 + v * 3 + 1] = fvacc[s][1] * SC_FV;
            g_fv[e * 48 + v * 3 + 2] = fvacc[s][2] * SC_FV;
        }
    }
#pragma unroll
    for (int c = 0; c < 4; ++c) {  // lat1w1
        f32x16 d = colstage<20>(b_lat1w1, lB, c, nl, q);
        silu16(d);
        d2b(d, lane, q, &hB[8 * c], &hB[8 * c + 4]);
    }
    half_t* gl1 = g_lat1 + (size_t)b * 4096;
    float sc = A_COLD * cut;
#pragma unroll
    for (int c = 0; c < 4; ++c) {  // lat1w2 + combine -> lat'
        f32x16 d = colstage<16>(b_lat1w2, hB, c, nl, q);
#pragma unroll
        for (int i = 0; i < 16; ++i) d[i] *= sc;
        float nw[8];
        d2b(d, lane, q, nw, nw + 4);
#pragma unroll
        for (int p = 0; p < 8; ++p) {
            float2 o = uph(lB[8 * c + p]);
            float2 nn2 = uph(nw[p]);
            lB[8 * c + p] = pkh(C_OLD * o.x + nn2.x, C_OLD * o.y + nn2.y);
        }
        *reinterpret_cast<half8*>(gl1 + ((4 * c + q) * 32 + nl) * 8) = mk8(&lB[8 * c]);
        *reinterpret_cast<half8*>(gl1 + ((4 * c + 2 + q) * 32 + nl) * 8) = mk8(&lB[8 * c + 4]);
    }
#pragma unroll
    for (int c = 0; c < 4; ++c) {  // e1w1 (K=128, lat' windows 0..7)
        f32x16 d = colstage<16>(b_e1w1, lB, c, nl, q);
        silu16(d);
        d2b(d, lane, q, &hB[8 * c], &hB[8 * c + 4]);
    }
    {  // e1w2 -> raw1 scatter
        f32x16 d = colstage<16>(b_e1w2, hB, 0, nl, q);
#pragma unroll
        for (int r = 0; r < 16; ++r) {
            int f = (r & 3) + 8 * (r >> 2) + 4 * q;
            int u = f >> 1;
            float val = d[r];
            if ((f & 1) == 0) {
                atomicAdd(&raw1[ce * 64 + u], val * ea.x);
            } else {
                atomicAdd(&raw1[ce * 64 + 16 + u * 3 + 0], val * ea.y);
                atomicAdd(&raw1[ce * 64 + 16 + u * 3 + 1], val * ea.z);
                atomicAdd(&raw1[ce * 64 + 16 + u * 3 + 2], val * ea.w);
            }
        }
    }
}

// =====================================================================
// K5: layer1 — gather, fw MLP, wv fold, output.
// =====================================================================
__global__ __launch_bounds__(64, 3) void k_layer1(
    const int* __restrict__ g_eidx, const float* __restrict__ g_fs,
    const float* __restrict__ g_fv, const float* __restrict__ ls1,
    const float* __restrict__ lv1,
    const half_t* __restrict__ b_flw1, const half_t* __restrict__ b_flw2,
    const half_t* __restrict__ b_gw1, const half_t* __restrict__ b_gw2,
    const half_t* __restrict__ g_lat1, float* __restrict__ g_out, int E) {
    __shared__ half_t sS[32 * SSD];
    __shared__ half_t Vsh[32 * VPH];
    __shared__ float fwS[32 * 17];
    __shared__ half_t fvS[32 * 50];
    const int lane = threadIdx.x, nl = lane & 31, q = lane >> 5;
    const int b = blockIdx.x, eb = b * 32, e = eb + nl;
    int ce = g_eidx[e];

    float lB[40];
    const half_t* gl1 = g_lat1 + (size_t)b * 4096;
#pragma unroll
    for (int h = 0; h < 8; ++h) {
        f32x4 v = *reinterpret_cast<const f32x4*>(gl1 + ((2 * h + q) * 32 + nl) * 8);
        lB[h * 4 + 0] = v[0]; lB[h * 4 + 1] = v[1];
        lB[h * 4 + 2] = v[2]; lB[h * 4 + 3] = v[3];
    }
#pragma unroll
    for (int mm = 0; mm < 8; ++mm) {
        int m = q * 8 + mm;
        float fs = g_fs[e * 16 + m];
        float fv0 = g_fv[e * 48 + m * 3 + 0];
        float fv1 = g_fv[e * 48 + m * 3 + 1];
        float fv2 = g_fv[e * 48 + m * 3 + 2];
        float es = ls1[ce * 16 + m];
        float ev0 = lv1[ce * 48 + m * 3 + 0];
        float ev1 = lv1[ce * 48 + m * 3 + 1];
        float ev2 = lv1[ce * 48 + m * 3 + 2];
        float s1 = fs * es;
        float s2 = (fv0 * ev0 + fv1 * ev1 + fv2 * ev2) * INV_S3;
        sS[nl * SSD + 2 * m + 0] = (half_t)s1;
        sS[nl * SSD + 2 * m + 1] = (half_t)s2;
        half_t* vp = Vsh + nl * VPH;
        vp[m * 3 + 0] = (half_t)(fs * ev0);
        vp[m * 3 + 1] = (half_t)(fs * ev1);
        vp[m * 3 + 2] = (half_t)(fs * ev2);
        vp[(16 + m) * 3 + 0] = (half_t)(fv0 * es);
        vp[(16 + m) * 3 + 1] = (half_t)(fv1 * es);
        vp[(16 + m) * 3 + 2] = (half_t)(fv2 * es);
        vp[(32 + m) * 3 + 0] = (half_t)((fv1 * ev2 - fv2 * ev1) * INV_S2);
        vp[(32 + m) * 3 + 1] = (half_t)((fv2 * ev0 - fv0 * ev2) * INV_S2);
        vp[(32 + m) * 3 + 2] = (half_t)((fv0 * ev1 - fv1 * ev0) * INV_S2);
    }
    __syncthreads();  // LDS producer->consumer join

#pragma unroll
    for (int j2 = 0; j2 < 4; ++j2) {
        lB[32 + j2] = ld_pk2(sS + nl * SSD + 8 * q + 2 * j2);
        lB[36 + j2] = ld_pk2(sS + nl * SSD + 16 + 8 * q + 2 * j2);
    }

    float hB[32];
#pragma unroll
    for (int c = 0; c < 4; ++c) {  // flw1
        f32x16 d = colstage<20>(b_flw1, lB, c, nl, q);
        silu16(d);
        d2b(d, lane, q, &hB[8 * c], &hB[8 * c + 4]);
    }
    {  // flw2 (N=16): rows f<16 valid (r 0..7)
        f32x16 d = colstage<16>(b_flw2, hB, 0, nl, q);
#pragma unroll
        for (int r = 0; r < 8; ++r) {
            int f = (r & 3) + 8 * (r >> 2) + 4 * q;
            fwS[nl * 17 + f] = d[r];
        }
    }
#pragma unroll
    for (int c = 0; c < 4; ++c) {  // gw1
        f32x16 d = colstage<20>(b_gw1, lB, c, nl, q);
        silu16(d);
        d2b(d, lane, q, &hB[8 * c], &hB[8 * c + 4]);
    }
    {  // gw2 wv fold: mtiles 16..39
        float fvacc[8][3];
#pragma unroll
        for (int s = 0; s < 8; ++s) fvacc[s][0] = fvacc[s][1] = fvacc[s][2] = 0.f;
        for (int c = 16; c < 40; ++c) {
            f32x16 d = colstage<16>(b_gw2, hB, c, nl, q);
            int w0 = 2 * c - 32, w1 = 2 * c - 31;
            const half_t* vp = Vsh + nl * VPH;
            float V00 = (float)vp[w0 * 3], V01 = (float)vp[w0 * 3 + 1], V02 = (float)vp[w0 * 3 + 2];
            float V10 = (float)vp[w1 * 3], V11 = (float)vp[w1 * 3 + 1], V12 = (float)vp[w1 * 3 + 2];
#pragma unroll
            for (int r = 0; r < 16; ++r) {
                int a = r >> 2, bb = r & 3, slot = (a & 1) * 4 + bb;
                float x0 = (a < 2) ? V00 : V10;
                float x1 = (a < 2) ? V01 : V11;
                float x2 = (a < 2) ? V02 : V12;
                fvacc[slot][0] = fmaf(x0, d[r], fvacc[slot][0]);
                fvacc[slot][1] = fmaf(x1, d[r], fvacc[slot][1]);
                fvacc[slot][2] = fmaf(x2, d[r], fvacc[slot][2]);
            }
        }
#pragma unroll
        for (int s = 0; s < 8; ++s) {
            int v = (s & 3) + 4 * q + 8 * (s >> 2);
            fvS[nl * 50 + v * 3 + 0] = (half_t)fvacc[s][0];
            fvS[nl * 50 + v * 3 + 1] = (half_t)fvacc[s][1];
            fvS[nl * 50 + v * 3 + 2] = (half_t)fvacc[s][2];
        }
    }
    __syncthreads();  // fwS/fvS ready before combine

    // output: lanes q==0 combine fw x fv for their edge
    if (q == 0) {
        float o0 = 0.f, o1 = 0.f, o2 = 0.f;
#pragma unroll
        for (int u = 0; u < 16; ++u) {
            float fw = fwS[nl * 17 + u];
            o0 = fmaf(fw, (float)fvS[nl * 50 + u * 3 + 0], o0);
            o1 = fmaf(fw, (float)fvS[nl * 50 + u * 3 + 1], o1);
            o2 = fmaf(fw, (float)fvS[nl * 50 + u * 3 + 2], o2);
        }
        g_out[e * 3 + 0] = o0 * SC_OUT;
        g_out[e * 3 + 1] = o1 * SC_OUT;
        g_out[e * 3 + 2] = o2 * SC_OUT;
    }
}

// =====================================================================
extern "C" void kernel_launch(void* const* d_in, const int* in_sizes, int n_in,
                              void* d_out, int out_size, void* d_ws, size_t ws_size,
                              hipStream_t stream) {
    const float* g_ea = (const float*)d_in[0];
    const float* g_na = (const float*)d_in[1];
    const float* g_emb = (const float*)d_in[2];
    const float* g_eu = (const float*)d_in[3];
    const int* g_eidx = (const int*)d_in[4];
    const float* w2b1 = (const float*)d_in[5];
    const float* w2b2 = (const float*)d_in[6];
    const float* lat1w1 = (const float*)d_in[7];
    const float* lat1w2 = (const float*)d_in[8];
    const float* e0w1 = (const float*)d_in[9];
    const float* e0w2 = (const float*)d_in[10];
    const float* e1w1 = (const float*)d_in[11];
    const float* e1w2 = (const float*)d_in[12];
    const float* l2w0w1 = (const float*)d_in[13];
    const float* l2w0w2 = (const float*)d_in[14];
    const float* l2w1w1 = (const float*)d_in[15];
    const float* l2w1w2 = (const float*)d_in[16];
    const float* envws = (const float*)d_in[17];
    const float* envwv = (const float*)d_in[18];
    const float* flw1 = (const float*)d_in[19];
    const float* flw2 = (const float*)d_in[20];
    float* out = (float*)d_out;

    const int E = in_sizes[3];       // 120000
    const int Nn = in_sizes[1] / 4;  // 5000
    const int nblk = E / 32;         // 3750

    float* p = (float*)d_ws;
    float* gfs = p;  p += (size_t)E * 16;
    float* gfv = p;  p += (size_t)E * 48;
    float* raw0 = p; p += (size_t)Nn * 64;
    float* raw1 = p; p += (size_t)Nn * 64;
    float* ls0 = p;  p += (size_t)Nn * 16;
    float* lv0 = p;  p += (size_t)Nn * 48;
    float* ls1 = p;  p += (size_t)Nn * 16;
    float* lv1 = p;  p += (size_t)Nn * 48;
    half_t* hp = (half_t*)p;
    half_t* lat0h = hp; hp += (size_t)nblk * 4096;
    half_t* lat1h = hp; hp += (size_t)nblk * 4096;

    const int KN[14][2] = {{16, 128}, {128, 128}, {128, 128}, {128, 64},
                           {160, 128}, {128, 128}, {128, 128}, {128, 32},
                           {160, 128}, {128, 1280}, {160, 128}, {128, 1280},
                           {160, 128}, {128, 16}};
    const float* srcs[14] = {w2b1, w2b2, e0w1, e0w2, lat1w1, lat1w2, e1w1, e1w2,
                             l2w0w1, l2w0w2, l2w1w1, l2w1w2, flw1, flw2};
    PackArgs pa;
    half_t* bptr[14];
    for (int i = 0; i < 14; ++i) {
        int K = KN[i][0], N = KN[i][1];
        int Npad = (N + 31) & ~31;
        bptr[i] = hp;
        hp += (size_t)K * Npad;
        pa.src[i] = srcs[i];
        pa.dst[i] = bptr[i];
        pa.K[i] = K;
        pa.N[i] = N;
    }

    k_pack<<<dim3(80, 14), 256, 0, stream>>>(pa);

    const int nzero = Nn * 128;
    k_zero<<<(nzero + 255) / 256, 256, 0, stream>>>(raw0, nzero);

    const int nb2 = (Nn * 16 + 255) / 256;

    k_edge_front<<<nblk, 64, 0, stream>>>(g_ea, g_na, g_emb, g_eu, g_eidx,
                                          bptr[0], bptr[1], bptr[2], bptr[3],
                                          lat0h, gfs, gfv, raw0, E);
    k_node_lin<<<nb2, 256, 0, stream>>>(raw0, envws, envwv, ls0, lv0, Nn);
    k_layer0<<<nblk, 64, 0, stream>>>(g_ea, g_eu, g_eidx, gfs, gfv, ls0, lv0,
                                      bptr[4], bptr[5], bptr[6], bptr[7],
                                      bptr[8], bptr[9], lat0h, lat1h, raw1, E);
    k_node_lin<<<nb2, 256, 0, stream>>>(raw1, envws + 256, envwv + 256, ls1, lv1, Nn);
    k_layer1<<<nblk, 64, 0, stream>>>(g_eidx, gfs, gfv, ls1, lv1,
                                      bptr[12], bptr[13], bptr[10], bptr[11],
                                      lat1h, out, E);
}

// Round 9
// 907.995 us; speedup vs baseline: 1.4196x; 1.0102x over previous
//
#include <hip/hip_runtime.h>

typedef _Float16 half_t;
typedef _Float16 half8 __attribute__((ext_vector_type(8)));
typedef _Float16 half2_t __attribute__((ext_vector_type(2)));
typedef float f32x16 __attribute__((ext_vector_type(16)));
typedef float f32x4 __attribute__((ext_vector_type(4)));

#define DEVINL __device__ __forceinline__

// ---------- constants ----------
#define INV_S3 0.57735026918962576f   // 1/sqrt(3)
#define INV_S2 0.70710678118654752f   // 1/sqrt(2)
#define C_OLD  0.89442719099991588f   // 1/sqrt(1.25)
#define A_COLD 0.44721359549995794f   // 0.5/sqrt(1.25)
#define SC_ENV 0.05590169943749474f   // (1/sqrt(20)) * (1/4)
#define SC_FS  0.17677669529663688f   // 1/sqrt(32)
#define SC_FV  0.14433756729740643f   // 1/sqrt(48)
#define SC_OUT 0.03608439182435161f   // (1/4)/sqrt(48) — includes the layer-1 fold scale
#define SSD 34                         // sS stride (halfs)
#define VPH 146                        // V stride (halfs)

DEVINL float silu_f(float x) { return x / (1.f + __expf(-x)); }

DEVINL float poly_cut(float u) {
    float u2 = u * u, u4 = u2 * u2, u6 = u4 * u2;
    float f = 1.f - 28.f * u6 + 48.f * u6 * u - 21.f * u6 * u2;
    return (u < 1.f) ? f : 0.f;
}

DEVINL float pkh(float a, float b) {  // pack 2 f32 -> half2 bits in a float (RNE)
    half2_t h; h[0] = (half_t)a; h[1] = (half_t)b;
    return __builtin_bit_cast(float, h);
}
DEVINL float2 uph(float p) {
    half2_t h = __builtin_bit_cast(half2_t, p);
    return make_float2((float)h[0], (float)h[1]);
}
DEVINL half8 mk8(const float* w) {
    f32x4 v = {w[0], w[1], w[2], w[3]};
    return __builtin_bit_cast(half8, v);
}
// type-safe: read two adjacent LDS halfs, return packed-as-float (no aliasing UB)
DEVINL float ld_pk2(const half_t* p) {
    half2_t h; h[0] = p[0]; h[1] = p[1];
    return __builtin_bit_cast(float, h);
}

// =====================================================================
// Edge-column MFMA stage: A = weights [M=features], B = edges (in regs).
// Weight pack: cell(mtile,kblk,m) at halfs[((mtile*KB+kblk)*32+m)*8+j]
// B windows: 4 packed floats per 16-k window; lane (n + 32q) holds k = 8q+j.
// D: lane owns edge col n = lane&31; row f = (r&3) + 8*(r>>2) + 4*(lane>>5).
// =====================================================================
template <int KB>  // K/8
DEVINL f32x16 colstage(const half_t* __restrict__ Wg, const float* B, int mtile,
                       int nl, int q) {
    const half_t* ap = Wg + (((size_t)mtile * KB + q) * 32 + nl) * 8;
    f32x16 acc;
#pragma unroll
    for (int i = 0; i < 16; ++i) acc[i] = 0.f;
#pragma unroll
    for (int h = 0; h < KB / 2; ++h) {
        half8 a = *reinterpret_cast<const half8*>(ap + h * 512);
        acc = __builtin_amdgcn_mfma_f32_32x32x16_f16(a, mk8(B + h * 4), acc, 0, 0, 0);
    }
    return acc;
}

DEVINL void silu16(f32x16& a) {
#pragma unroll
    for (int i = 0; i < 16; ++i) a[i] = silu_f(a[i]);
}

// D (f32 regs) -> B-frag for next stage: two k-windows of 4 packed floats.
DEVINL void d2b(const f32x16& d, int lane, int q, float* wA, float* wB) {
    float pk[8];
#pragma unroll
    for (int a2 = 0; a2 < 4; ++a2) {
        pk[a2 * 2 + 0] = pkh(d[4 * a2 + 0], d[4 * a2 + 1]);
        pk[a2 * 2 + 1] = pkh(d[4 * a2 + 2], d[4 * a2 + 3]);
    }
#pragma unroll
    for (int t = 0; t < 2; ++t) {
        float k0 = q ? pk[(2 * t + 1) * 2 + 0] : pk[(2 * t) * 2 + 0];
        float k1 = q ? pk[(2 * t + 1) * 2 + 1] : pk[(2 * t) * 2 + 1];
        float s0 = q ? pk[(2 * t) * 2 + 0] : pk[(2 * t + 1) * 2 + 0];
        float s1 = q ? pk[(2 * t) * 2 + 1] : pk[(2 * t + 1) * 2 + 1];
        float r0 = __shfl(s0, lane ^ 32, 64);
        float r1 = __shfl(s1, lane ^ 32, 64);
        float* w = t ? wB : wA;
        w[0] = q ? r0 : k0;
        w[1] = q ? r1 : k1;
        w[2] = q ? k0 : r0;
        w[3] = q ? k1 : r1;
    }
}

// =====================================================================
__global__ __launch_bounds__(256) void k_zero(float* __restrict__ p, int n) {
    int i = blockIdx.x * 256 + threadIdx.x;
    if (i < n) p[i] = 0.f;
}

// =====================================================================
// Weight pack: f32 [K][N] row-major -> fp16 fragment layout (N padded to 32).
// =====================================================================
struct PackArgs {
    const float* src[14];
    half_t* dst[14];
    int K[14];
    int N[14];
};

__global__ __launch_bounds__(256) void k_pack(PackArgs pa) {
    int mi = blockIdx.y;
    int K = pa.K[mi], N = pa.N[mi];
    int Npad = (N + 31) & ~31;
    int KB = K >> 3;
    int cells = KB * Npad;
    int cell = blockIdx.x * 256 + threadIdx.x;
    if (cell >= cells) return;
    int nn = cell & 31, r2 = cell >> 5;
    int kblk = r2 % KB, ntile = r2 / KB;
    int n = ntile * 32 + nn;
    const float* W = pa.src[mi];
    half8 v;
#pragma unroll
    for (int j = 0; j < 8; ++j) {
        int k = kblk * 8 + j;
        v[j] = (half_t)((n < N) ? W[k * N + n] : 0.f);
    }
    *reinterpret_cast<half8*>(pa.dst[mi] + (size_t)cell * 8) = v;
}

// =====================================================================
// K1: front. 2 independent waves/block, 32 edges each, no LDS.
// =====================================================================
__global__ __launch_bounds__(128, 4) void k_edge_front(
    const float* __restrict__ g_ea, const float* __restrict__ g_na,
    const float* __restrict__ g_emb, const float* __restrict__ g_eu,
    const int* __restrict__ g_eidx,
    const half_t* __restrict__ b_w2b1, const half_t* __restrict__ b_w2b2,
    const half_t* __restrict__ b_e0w1, const half_t* __restrict__ b_e0w2,
    half_t* __restrict__ g_lat0, float* __restrict__ g_fs, float* __restrict__ g_fv,
    float* __restrict__ raw0, int E) {
    const int lane = threadIdx.x & 63, nl = lane & 31, q = lane >> 5;
    const int g = blockIdx.x * 2 + (threadIdx.x >> 6);
    const int e = g * 32 + nl;
    int ce = g_eidx[e];
    float4 ea = *reinterpret_cast<const float4*>(g_ea + e * 4);
    float cut = poly_cut(g_eu[e]);

    float xw[4];
    if (q == 0) {
        int ne = g_eidx[E + e];
        float4 nc = *reinterpret_cast<const float4*>(g_na + ce * 4);
        float4 nn = *reinterpret_cast<const float4*>(g_na + ne * 4);
        xw[0] = pkh(nc.x, nc.y); xw[1] = pkh(nc.z, nc.w);
        xw[2] = pkh(nn.x, nn.y); xw[3] = pkh(nn.z, nn.w);
    } else {
        float4 m0 = *reinterpret_cast<const float4*>(g_emb + e * 8);
        float4 m1 = *reinterpret_cast<const float4*>(g_emb + e * 8 + 4);
        xw[0] = pkh(m0.x, m0.y); xw[1] = pkh(m0.z, m0.w);
        xw[2] = pkh(m1.x, m1.y); xw[3] = pkh(m1.z, m1.w);
    }

    float hB[32], lB[32];
#pragma unroll
    for (int c = 0; c < 4; ++c) {  // w2b1: K=16
        f32x16 d = colstage<2>(b_w2b1, xw, c, nl, q);
        silu16(d);
        d2b(d, lane, q, &hB[8 * c], &hB[8 * c + 4]);
    }
    half_t* gl = g_lat0 + (size_t)g * 4096;
#pragma unroll
    for (int c = 0; c < 4; ++c) {  // w2b2 -> lat = cut*D
        f32x16 d = colstage<16>(b_w2b2, hB, c, nl, q);
#pragma unroll
        for (int i = 0; i < 16; ++i) d[i] *= cut;
        d2b(d, lane, q, &lB[8 * c], &lB[8 * c + 4]);
        *reinterpret_cast<half8*>(gl + ((4 * c + q) * 32 + nl) * 8) = mk8(&lB[8 * c]);
        *reinterpret_cast<half8*>(gl + ((4 * c + 2 + q) * 32 + nl) * 8) = mk8(&lB[8 * c + 4]);
    }
#pragma unroll
    for (int c = 0; c < 4; ++c) {  // e0w1
        f32x16 d = colstage<16>(b_e0w1, lB, c, nl, q);
        silu16(d);
        d2b(d, lane, q, &hB[8 * c], &hB[8 * c + 4]);
    }
    {  // e0w2 both mtiles interleaved
        f32x16 d0 = colstage<16>(b_e0w2, hB, 0, nl, q);
        f32x16 d1 = colstage<16>(b_e0w2, hB, 1, nl, q);
#pragma unroll
        for (int r = 0; r < 16; ++r) {
            int f = (r & 3) + 8 * (r >> 2) + 4 * q;
            int u = f >> 1;
            float v0 = d0[r], v1 = d1[r];
            if ((f & 1) == 0) {
                g_fs[e * 16 + u] = v0 * ea.x;
                atomicAdd(&raw0[ce * 64 + u], v1 * ea.x);
            } else {
                g_fv[e * 48 + u * 3 + 0] = v0 * ea.y;
                g_fv[e * 48 + u * 3 + 1] = v0 * ea.z;
                g_fv[e * 48 + u * 3 + 2] = v0 * ea.w;
                atomicAdd(&raw0[ce * 64 + 16 + u * 3 + 0], v1 * ea.y);
                atomicAdd(&raw0[ce * 64 + 16 + u * 3 + 1], v1 * ea.z);
                atomicAdd(&raw0[ce * 64 + 16 + u * 3 + 2], v1 * ea.w);
            }
        }
    }
}

// =====================================================================
// K2: per-node env linear (f32).
// =====================================================================
__global__ __launch_bounds__(256) void k_node_lin(
    const float* __restrict__ raw, const float* __restrict__ wls,
    const float* __restrict__ wlv, float* __restrict__ ls, float* __restrict__ lv,
    int Nn) {
    int gid = blockIdx.x * 256 + threadIdx.x;
    if (gid >= Nn * 16) return;
    int n = gid >> 4, v = gid & 15;
    float as = 0.f, a0 = 0.f, a1 = 0.f, a2 = 0.f;
    const float* rp = raw + n * 64;
#pragma unroll
    for (int u = 0; u < 16; ++u) {
        float w1 = wls[u * 16 + v];
        float w2 = wlv[u * 16 + v];
        as = fmaf(rp[u], w1, as);
        a0 = fmaf(rp[16 + u * 3 + 0], w2, a0);
        a1 = fmaf(rp[16 + u * 3 + 1], w2, a1);
        a2 = fmaf(rp[16 + u * 3 + 2], w2, a2);
    }
    ls[n * 16 + v] = as * SC_ENV;
    lv[n * 48 + v * 3 + 0] = a0 * SC_ENV;
    lv[n * 48 + v * 3 + 1] = a1 * SC_ENV;
    lv[n * 48 + v * 3 + 2] = a2 * SC_ENV;
}

// =====================================================================
// K3: layer0 — 2 waves/block, per-wave LDS slices, unroll-2 folds.
// =====================================================================
__global__ __launch_bounds__(128, 3) void k_layer0(
    const float* __restrict__ g_ea, const float* __restrict__ g_eu,
    const int* __restrict__ g_eidx,
    float* g_fs, float* g_fv,
    const float* __restrict__ ls0, const float* __restrict__ lv0,
    const half_t* __restrict__ b_lat1w1, const half_t* __restrict__ b_lat1w2,
    const half_t* __restrict__ b_e1w1, const half_t* __restrict__ b_e1w2,
    const half_t* __restrict__ b_gw1, const half_t* __restrict__ b_gw2,
    const half_t* __restrict__ g_lat0, half_t* __restrict__ g_lat1,
    float* __restrict__ raw1, int E) {
    __shared__ half_t sSb[2 * 32 * SSD];
    __shared__ half_t Vshb[2 * 32 * VPH];
    const int lane = threadIdx.x & 63, nl = lane & 31, q = lane >> 5;
    const int w = threadIdx.x >> 6;
    const int g = blockIdx.x * 2 + w;
    const int e = g * 32 + nl;
    half_t* sS = sSb + w * 32 * SSD;
    half_t* Vsh = Vshb + w * 32 * VPH;
    int ce = g_eidx[e];
    float4 ea = *reinterpret_cast<const float4*>(g_ea + e * 4);
    float cut = poly_cut(g_eu[e]);

    float lB[40];
    const half_t* gl0 = g_lat0 + (size_t)g * 4096;
#pragma unroll
    for (int h = 0; h < 8; ++h) {
        f32x4 v = *reinterpret_cast<const f32x4*>(gl0 + ((2 * h + q) * 32 + nl) * 8);
        lB[h * 4 + 0] = v[0]; lB[h * 4 + 1] = v[1];
        lB[h * 4 + 2] = v[2]; lB[h * 4 + 3] = v[3];
    }
    // gather env0: lane handles its edge, m = 8q..8q+7
#pragma unroll
    for (int mm = 0; mm < 8; ++mm) {
        int m = q * 8 + mm;
        float fs = g_fs[e * 16 + m];
        float fv0 = g_fv[e * 48 + m * 3 + 0];
        float fv1 = g_fv[e * 48 + m * 3 + 1];
        float fv2 = g_fv[e * 48 + m * 3 + 2];
        float es = ls0[ce * 16 + m];
        float ev0 = lv0[ce * 48 + m * 3 + 0];
        float ev1 = lv0[ce * 48 + m * 3 + 1];
        float ev2 = lv0[ce * 48 + m * 3 + 2];
        float s1 = fs * es;
        float s2 = (fv0 * ev0 + fv1 * ev1 + fv2 * ev2) * INV_S3;
        sS[nl * SSD + 2 * m + 0] = (half_t)s1;
        sS[nl * SSD + 2 * m + 1] = (half_t)s2;
        half_t* vp = Vsh + nl * VPH;
        vp[m * 3 + 0] = (half_t)(fs * ev0);
        vp[m * 3 + 1] = (half_t)(fs * ev1);
        vp[m * 3 + 2] = (half_t)(fs * ev2);
        vp[(16 + m) * 3 + 0] = (half_t)(fv0 * es);
        vp[(16 + m) * 3 + 1] = (half_t)(fv1 * es);
        vp[(16 + m) * 3 + 2] = (half_t)(fv2 * es);
        vp[(32 + m) * 3 + 0] = (half_t)((fv1 * ev2 - fv2 * ev1) * INV_S2);
        vp[(32 + m) * 3 + 1] = (half_t)((fv2 * ev0 - fv0 * ev2) * INV_S2);
        vp[(32 + m) * 3 + 2] = (half_t)((fv0 * ev1 - fv1 * ev0) * INV_S2);
    }
    __syncthreads();  // LDS producer->consumer join (compiler fence)

    // latent windows 8,9 (scalars)
#pragma unroll
    for (int j2 = 0; j2 < 4; ++j2) {
        lB[32 + j2] = ld_pk2(sS + nl * SSD + 8 * q + 2 * j2);
        lB[36 + j2] = ld_pk2(sS + nl * SSD + 16 + 8 * q + 2 * j2);
    }

    float hB[32];
#pragma unroll
    for (int c = 0; c < 4; ++c) {  // gw1
        f32x16 d = colstage<20>(b_gw1, lB, c, nl, q);
        silu16(d);
        d2b(d, lane, q, &hB[8 * c], &hB[8 * c + 4]);
    }
    {  // gw2 ws fold: mtiles 0..15, unroll-2 (independent chains)
        float fsacc[8];
#pragma unroll
        for (int s = 0; s < 8; ++s) fsacc[s] = 0.f;
        for (int c = 0; c < 16; c += 2) {
            f32x16 d0 = colstage<16>(b_gw2, hB, c, nl, q);
            f32x16 d1 = colstage<16>(b_gw2, hB, c + 1, nl, q);
#pragma unroll
            for (int cc = 0; cc < 2; ++cc) {
                const f32x16& d = cc ? d1 : d0;
                int pu0 = 2 * (c + cc), pu1 = pu0 + 1;
                float S0 = (float)sS[nl * SSD + 2 * (pu0 & 15) + (pu0 >> 4)];
                float S1 = (float)sS[nl * SSD + 2 * (pu1 & 15) + (pu1 >> 4)];
#pragma unroll
                for (int r = 0; r < 16; ++r) {
                    int a = r >> 2, bb = r & 3, slot = (a & 1) * 4 + bb;
                    fsacc[slot] = fmaf((a < 2) ? S0 : S1, d[r], fsacc[slot]);
                }
            }
        }
#pragma unroll
        for (int s = 0; s < 8; ++s) {
            int v = (s & 3) + 4 * q + 8 * (s >> 2);
            g_fs[e * 16 + v] = fsacc[s] * SC_FS;
        }
    }
    {  // gw2 wv fold: mtiles 16..39, unroll-2
        float fvacc[8][3];
#pragma unroll
        for (int s = 0; s < 8; ++s) fvacc[s][0] = fvacc[s][1] = fvacc[s][2] = 0.f;
        for (int c = 16; c < 40; c += 2) {
            f32x16 d0 = colstage<16>(b_gw2, hB, c, nl, q);
            f32x16 d1 = colstage<16>(b_gw2, hB, c + 1, nl, q);
#pragma unroll
            for (int cc = 0; cc < 2; ++cc) {
                const f32x16& d = cc ? d1 : d0;
                int w0 = 2 * (c + cc) - 32, w1 = w0 + 1;
                const half_t* vp = Vsh + nl * VPH;
                float V00 = (float)vp[w0 * 3], V01 = (float)vp[w0 * 3 + 1], V02 = (float)vp[w0 * 3 + 2];
                float V10 = (float)vp[w1 * 3], V11 = (float)vp[w1 * 3 + 1], V12 = (float)vp[w1 * 3 + 2];
#pragma unroll
                for (int r = 0; r < 16; ++r) {
                    int a = r >> 2, bb = r & 3, slot = (a & 1) * 4 + bb;
                    float x0 = (a < 2) ? V00 : V10;
                    float x1 = (a < 2) ? V01 : V11;
                    float x2 = (a < 2) ? V02 : V12;
                    fvacc[slot][0] = fmaf(x0, d[r], fvacc[slot][0]);
                    fvacc[slot][1] = fmaf(x1, d[r], fvacc[slot][1]);
                    fvacc[slot][2] = fmaf(x2, d[r], fvacc[slot][2]);
                }
            }
        }
#pragma unroll
        for (int s = 0; s < 8; ++s) {
            int v = (s & 3) + 4 * q + 8 * (s >> 2);
            g_fv[e * 48 + v * 3 + 0] = fvacc[s][0] * SC_FV;
            g_fv[e * 48 + v * 3 + 1] = fvacc[s][1] * SC_FV;
            g_fv[e * 48 + v * 3 + 2] = fvacc[s][2] * SC_FV;
        }
    }
#pragma unroll
    for (int c = 0; c < 4; ++c) {  // lat1w1
        f32x16 d = colstage<20>(b_lat1w1, lB, c, nl, q);
        silu16(d);
        d2b(d, lane, q, &hB[8 * c], &hB[8 * c + 4]);
    }
    half_t* gl1 = g_lat1 + (size_t)g * 4096;
    float sc = A_COLD * cut;
#pragma unroll
    for (int c = 0; c < 4; ++c) {  // lat1w2 + combine -> lat'
        f32x16 d = colstage<16>(b_lat1w2, hB, c, nl, q);
#pragma unroll
        for (int i = 0; i < 16; ++i) d[i] *= sc;
        float nw[8];
        d2b(d, lane, q, nw, nw + 4);
#pragma unroll
        for (int p = 0; p < 8; ++p) {
            float2 o = uph(lB[8 * c + p]);
            float2 nn2 = uph(nw[p]);
            lB[8 * c + p] = pkh(C_OLD * o.x + nn2.x, C_OLD * o.y + nn2.y);
        }
        *reinterpret_cast<half8*>(gl1 + ((4 * c + q) * 32 + nl) * 8) = mk8(&lB[8 * c]);
        *reinterpret_cast<half8*>(gl1 + ((4 * c + 2 + q) * 32 + nl) * 8) = mk8(&lB[8 * c + 4]);
    }
#pragma unroll
    for (int c = 0; c < 4; ++c) {  // e1w1 (K=128, lat' windows 0..7)
        f32x16 d = colstage<16>(b_e1w1, lB, c, nl, q);
        silu16(d);
        d2b(d, lane, q, &hB[8 * c], &hB[8 * c + 4]);
    }
    {  // e1w2 -> raw1 scatter
        f32x16 d = colstage<16>(b_e1w2, hB, 0, nl, q);
#pragma unroll
        for (int r = 0; r < 16; ++r) {
            int f = (r & 3) + 8 * (r >> 2) + 4 * q;
            int u = f >> 1;
            float val = d[r];
            if ((f & 1) == 0) {
                atomicAdd(&raw1[ce * 64 + u], val * ea.x);
            } else {
                atomicAdd(&raw1[ce * 64 + 16 + u * 3 + 0], val * ea.y);
                atomicAdd(&raw1[ce * 64 + 16 + u * 3 + 1], val * ea.z);
                atomicAdd(&raw1[ce * 64 + 16 + u * 3 + 2], val * ea.w);
            }
        }
    }
}

// =====================================================================
// K5: layer1 — 2 waves/block; fw/fv combine in registers + shfl.
// =====================================================================
__global__ __launch_bounds__(128, 3) void k_layer1(
    const int* __restrict__ g_eidx, const float* __restrict__ g_fs,
    const float* __restrict__ g_fv, const float* __restrict__ ls1,
    const float* __restrict__ lv1,
    const half_t* __restrict__ b_flw1, const half_t* __restrict__ b_flw2,
    const half_t* __restrict__ b_gw1, const half_t* __restrict__ b_gw2,
    const half_t* __restrict__ g_lat1, float* __restrict__ g_out, int E) {
    __shared__ half_t sSb[2 * 32 * SSD];
    __shared__ half_t Vshb[2 * 32 * VPH];
    const int lane = threadIdx.x & 63, nl = lane & 31, q = lane >> 5;
    const int w = threadIdx.x >> 6;
    const int g = blockIdx.x * 2 + w;
    const int e = g * 32 + nl;
    half_t* sS = sSb + w * 32 * SSD;
    half_t* Vsh = Vshb + w * 32 * VPH;
    int ce = g_eidx[e];

    float lB[40];
    const half_t* gl1 = g_lat1 + (size_t)g * 4096;
#pragma unroll
    for (int h = 0; h < 8; ++h) {
        f32x4 v = *reinterpret_cast<const f32x4*>(gl1 + ((2 * h + q) * 32 + nl) * 8);
        lB[h * 4 + 0] = v[0]; lB[h * 4 + 1] = v[1];
        lB[h * 4 + 2] = v[2]; lB[h * 4 + 3] = v[3];
    }
#pragma unroll
    for (int mm = 0; mm < 8; ++mm) {
        int m = q * 8 + mm;
        float fs = g_fs[e * 16 + m];
        float fv0 = g_fv[e * 48 + m * 3 + 0];
        float fv1 = g_fv[e * 48 + m * 3 + 1];
        float fv2 = g_fv[e * 48 + m * 3 + 2];
        float es = ls1[ce * 16 + m];
        float ev0 = lv1[ce * 48 + m * 3 + 0];
        float ev1 = lv1[ce * 48 + m * 3 + 1];
        float ev2 = lv1[ce * 48 + m * 3 + 2];
        float s1 = fs * es;
        float s2 = (fv0 * ev0 + fv1 * ev1 + fv2 * ev2) * INV_S3;
        sS[nl * SSD + 2 * m + 0] = (half_t)s1;
        sS[nl * SSD + 2 * m + 1] = (half_t)s2;
        half_t* vp = Vsh + nl * VPH;
        vp[m * 3 + 0] = (half_t)(fs * ev0);
        vp[m * 3 + 1] = (half_t)(fs * ev1);
        vp[m * 3 + 2] = (half_t)(fs * ev2);
        vp[(16 + m) * 3 + 0] = (half_t)(fv0 * es);
        vp[(16 + m) * 3 + 1] = (half_t)(fv1 * es);
        vp[(16 + m) * 3 + 2] = (half_t)(fv2 * es);
        vp[(32 + m) * 3 + 0] = (half_t)((fv1 * ev2 - fv2 * ev1) * INV_S2);
        vp[(32 + m) * 3 + 1] = (half_t)((fv2 * ev0 - fv0 * ev2) * INV_S2);
        vp[(32 + m) * 3 + 2] = (half_t)((fv0 * ev1 - fv1 * ev0) * INV_S2);
    }
    __syncthreads();  // LDS producer->consumer join

#pragma unroll
    for (int j2 = 0; j2 < 4; ++j2) {
        lB[32 + j2] = ld_pk2(sS + nl * SSD + 8 * q + 2 * j2);
        lB[36 + j2] = ld_pk2(sS + nl * SSD + 16 + 8 * q + 2 * j2);
    }

    float hB[32];
#pragma unroll
    for (int c = 0; c < 4; ++c) {  // flw1
        f32x16 d = colstage<20>(b_flw1, lB, c, nl, q);
        silu16(d);
        d2b(d, lane, q, &hB[8 * c], &hB[8 * c + 4]);
    }
    float fw[8];
    {  // flw2 (N=16): lane keeps its 8 fw values (f = (r&3)+8*(r>>2)+4q, r<8)
        f32x16 d = colstage<16>(b_flw2, hB, 0, nl, q);
#pragma unroll
        for (int r = 0; r < 8; ++r) fw[r] = d[r];
    }
#pragma unroll
    for (int c = 0; c < 4; ++c) {  // gw1
        f32x16 d = colstage<20>(b_gw1, lB, c, nl, q);
        silu16(d);
        d2b(d, lane, q, &hB[8 * c], &hB[8 * c + 4]);
    }
    {  // gw2 wv fold: mtiles 16..39, unroll-2; combine with fw in regs
        float fvacc[8][3];
#pragma unroll
        for (int s = 0; s < 8; ++s) fvacc[s][0] = fvacc[s][1] = fvacc[s][2] = 0.f;
        for (int c = 16; c < 40; c += 2) {
            f32x16 d0 = colstage<16>(b_gw2, hB, c, nl, q);
            f32x16 d1 = colstage<16>(b_gw2, hB, c + 1, nl, q);
#pragma unroll
            for (int cc = 0; cc < 2; ++cc) {
                const f32x16& d = cc ? d1 : d0;
                int w0 = 2 * (c + cc) - 32, w1 = w0 + 1;
                const half_t* vp = Vsh + nl * VPH;
                float V00 = (float)vp[w0 * 3], V01 = (float)vp[w0 * 3 + 1], V02 = (float)vp[w0 * 3 + 2];
                float V10 = (float)vp[w1 * 3], V11 = (float)vp[w1 * 3 + 1], V12 = (float)vp[w1 * 3 + 2];
#pragma unroll
                for (int r = 0; r < 16; ++r) {
                    int a = r >> 2, bb = r & 3, slot = (a & 1) * 4 + bb;
                    float x0 = (a < 2) ? V00 : V10;
                    float x1 = (a < 2) ? V01 : V11;
                    float x2 = (a < 2) ? V02 : V12;
                    fvacc[slot][0] = fmaf(x0, d[r], fvacc[slot][0]);
                    fvacc[slot][1] = fmaf(x1, d[r], fvacc[slot][1]);
                    fvacc[slot][2] = fmaf(x2, d[r], fvacc[slot][2]);
                }
            }
        }
        // out[e][i] = SC_OUT * sum_u fw[u] * fold_fv[u][i]
        // (SC_OUT = inv_sm/sqrt(48) already contains the layer-1 fold scale)
        // slot s of this lane pairs with fw[s] (same u = (s&3)+4q+8*(s>>2))
        float o0 = 0.f, o1 = 0.f, o2 = 0.f;
#pragma unroll
        for (int s = 0; s < 8; ++s) {
            o0 = fmaf(fw[s], fvacc[s][0], o0);
            o1 = fmaf(fw[s], fvacc[s][1], o1);
            o2 = fmaf(fw[s], fvacc[s][2], o2);
        }
        o0 += __shfl(o0, lane ^ 32, 64);
        o1 += __shfl(o1, lane ^ 32, 64);
        o2 += __shfl(o2, lane ^ 32, 64);
        if (q == 0) {
            g_out[e * 3 + 0] = o0 * SC_OUT;
            g_out[e * 3 + 1] = o1 * SC_OUT;
            g_out[e * 3 + 2] = o2 * SC_OUT;
        }
    }
}

// =====================================================================
extern "C" void kernel_launch(void* const* d_in, const int* in_sizes, int n_in,
                              void* d_out, int out_size, void* d_ws, size_t ws_size,
                              hipStream_t stream) {
    const float* g_ea = (const float*)d_in[0];
    const float* g_na = (const float*)d_in[1];
    const float* g_emb = (const float*)d_in[2];
    const float* g_eu = (const float*)d_in[3];
    const int* g_eidx = (const int*)d_in[4];
    const float* w2b1 = (const float*)d_in[5];
    const float* w2b2 = (const float*)d_in[6];
    const float* lat1w1 = (const float*)d_in[7];
    const float* lat1w2 = (const float*)d_in[8];
    const float* e0w1 = (const float*)d_in[9];
    const float* e0w2 = (const float*)d_in[10];
    const float* e1w1 = (const float*)d_in[11];
    const float* e1w2 = (const float*)d_in[12];
    const float* l2w0w1 = (const float*)d_in[13];
    const float* l2w0w2 = (const float*)d_in[14];
    const float* l2w1w1 = (const float*)d_in[15];
    const float* l2w1w2 = (const float*)d_in[16];
    const float* envws = (const float*)d_in[17];
    const float* envwv = (const float*)d_in[18];
    const float* flw1 = (const float*)d_in[19];
    const float* flw2 = (const float*)d_in[20];
    float* out = (float*)d_out;

    const int E = in_sizes[3];       // 120000
    const int Nn = in_sizes[1] / 4;  // 5000
    const int nblk = E / 32;         // 3750
    const int nblk2 = nblk / 2;      // 1875 (E divisible by 64)

    float* p = (float*)d_ws;
    float* gfs = p;  p += (size_t)E * 16;
    float* gfv = p;  p += (size_t)E * 48;
    float* raw0 = p; p += (size_t)Nn * 64;
    float* raw1 = p; p += (size_t)Nn * 64;
    float* ls0 = p;  p += (size_t)Nn * 16;
    float* lv0 = p;  p += (size_t)Nn * 48;
    float* ls1 = p;  p += (size_t)Nn * 16;
    float* lv1 = p;  p += (size_t)Nn * 48;
    half_t* hp = (half_t*)p;
    half_t* lat0h = hp; hp += (size_t)nblk * 4096;
    half_t* lat1h = hp; hp += (size_t)nblk * 4096;

    const int KN[14][2] = {{16, 128}, {128, 128}, {128, 128}, {128, 64},
                           {160, 128}, {128, 128}, {128, 128}, {128, 32},
                           {160, 128}, {128, 1280}, {160, 128}, {128, 1280},
                           {160, 128}, {128, 16}};
    const float* srcs[14] = {w2b1, w2b2, e0w1, e0w2, lat1w1, lat1w2, e1w1, e1w2,
                             l2w0w1, l2w0w2, l2w1w1, l2w1w2, flw1, flw2};
    PackArgs pa;
    half_t* bptr[14];
    for (int i = 0; i < 14; ++i) {
        int K = KN[i][0], N = KN[i][1];
        int Npad = (N + 31) & ~31;
        bptr[i] = hp;
        hp += (size_t)K * Npad;
        pa.src[i] = srcs[i];
        pa.dst[i] = bptr[i];
        pa.K[i] = K;
        pa.N[i] = N;
    }

    k_pack<<<dim3(80, 14), 256, 0, stream>>>(pa);

    const int nzero = Nn * 128;
    k_zero<<<(nzero + 255) / 256, 256, 0, stream>>>(raw0, nzero);

    const int nb2 = (Nn * 16 + 255) / 256;

    k_edge_front<<<nblk2, 128, 0, stream>>>(g_ea, g_na, g_emb, g_eu, g_eidx,
                                            bptr[0], bptr[1], bptr[2], bptr[3],
                                            lat0h, gfs, gfv, raw0, E);
    k_node_lin<<<nb2, 256, 0, stream>>>(raw0, envws, envwv, ls0, lv0, Nn);
    k_layer0<<<nblk2, 128, 0, stream>>>(g_ea, g_eu, g_eidx, gfs, gfv, ls0, lv0,
                                        bptr[4], bptr[5], bptr[6], bptr[7],
                                        bptr[8], bptr[9], lat0h, lat1h, raw1, E);
    k_node_lin<<<nb2, 256, 0, stream>>>(raw1, envws + 256, envwv + 256, ls1, lv1, Nn);
    k_layer1<<<nblk2, 128, 0, stream>>>(g_eidx, gfs, gfv, ls1, lv1,
                                        bptr[12], bptr[13], bptr[10], bptr[11],
                                        lat1h, out, E);
}